// Round 16
// baseline (171.330 us; speedup 1.0000x reference)
//
#include <hip/hip_runtime.h>
#include <stdint.h>

typedef unsigned short u16;
typedef __bf16 bfrag __attribute__((ext_vector_type(8)));   // 8 x bf16 = 4 VGPRs (MFMA A/B frag)
typedef float f32x4 __attribute__((ext_vector_type(4)));    // MFMA C/D frag
typedef u16 u16x4 __attribute__((ext_vector_type(4)));

__device__ __forceinline__ float bf2f(u16 u) {
  union { unsigned i; float f; } x; x.i = ((unsigned)u) << 16; return x.f;
}
__device__ __forceinline__ u16 f2bf(float f) {
  union { unsigned i; float f; } x; x.f = f;
  unsigned r = x.i + 0x7fffu + ((x.i >> 16) & 1u);   // RNE
  return (u16)(r >> 16);
}
// pure-C bf16 pair pack (inline-asm cvt_pk was implicated in the round-5 failure)
__device__ __forceinline__ unsigned packbf(float lo, float hi) {
  return (unsigned)f2bf(lo) | ((unsigned)f2bf(hi) << 16);
}

__device__ __forceinline__ f32x4 mfma16(bfrag a, bfrag b, f32x4 c) {
  return __builtin_amdgcn_mfma_f32_16x16x32_bf16(a, b, c, 0, 0, 0);
}

// async global->LDS, 16B per lane. LDS dest = wave-uniform base + lane*16.
__device__ __forceinline__ void gl_lds16(const u16* g, const u16* l) {
  __builtin_amdgcn_global_load_lds(
      (const __attribute__((address_space(1))) unsigned int*)g,
      (__attribute__((address_space(3))) unsigned int*)l, 16, 0, 0);
}

// XCD-bijective block swizzle (nwg must be a multiple of 8 — all our grids are).
__device__ __forceinline__ void xcd_swizzle(int& bx, int& by) {
  int gx = gridDim.x, nwg = gx * gridDim.y;
  int flat = by * gx + bx;
  int cpx = nwg >> 3;
  int swz = (flat & 7) * cpx + (flat >> 3);
  bx = swz % gx;
  by = swz / gx;
}

// ---------------- fused weight transposes: 3 segments, one launch ----------------
__global__ __launch_bounds__(256) void k_transpose3(const float* __restrict__ i0,
                                                    const float* __restrict__ i1,
                                                    const float* __restrict__ i2,
                                                    u16* __restrict__ o0,
                                                    u16* __restrict__ o1,
                                                    u16* __restrict__ o2) {
  __shared__ u16 tile[32][33];
  int bid = blockIdx.x;
  int seg = bid >> 11, tt = bid & 2047;   // 2048 tiles per segment
  const float* in;
  u16* out;
  int R, C, bx, by;
  if (seg == 0)      { in = i0; out = o0; R = 2048; C = 1024; bx = tt & 31; by = tt >> 5; }
  else if (seg == 1) { in = i1; out = o1; R = 1024; C = 2048; bx = tt & 63; by = tt >> 6; }
  else               { in = i2; out = o2; R = 1024; C = 2048; bx = tt & 63; by = tt >> 6; }
  int c0 = bx * 32, r0 = by * 32;
  int tx = threadIdx.x, ty = threadIdx.y;   // (32,8)
#pragma unroll
  for (int i = 0; i < 4; ++i)
    tile[ty + i * 8][tx] = f2bf(in[(size_t)(r0 + ty + i * 8) * C + c0 + tx]);
  __syncthreads();
#pragma unroll
  for (int i = 0; i < 4; ++i)
    out[(size_t)(c0 + ty + i * 8) * R + r0 + tx] = tile[tx][ty + i * 8];
}

// ---------------- cast f32 -> bf16, 8 elems/thread ----------------
__global__ __launch_bounds__(256) void k_cast(const float* __restrict__ in,
                                              u16* __restrict__ out, int n8) {
  int i = blockIdx.x * 256 + threadIdx.x;
  if (i >= n8) return;
  float4 a = *(const float4*)(in + (size_t)i * 8);
  float4 b = *(const float4*)(in + (size_t)i * 8 + 4);
  uint4 ov; u16* po = (u16*)&ov;
  po[0] = f2bf(a.x); po[1] = f2bf(a.y); po[2] = f2bf(a.z); po[3] = f2bf(a.w);
  po[4] = f2bf(b.x); po[5] = f2bf(b.y); po[6] = f2bf(b.z); po[7] = f2bf(b.w);
  *(uint4*)(out + (size_t)i * 8) = ov;
}

// ---------------- LayerNorm over last dim (2048), f32 in -> bf16 out ----------------
__global__ __launch_bounds__(256) void k_layernorm(const float* __restrict__ y,
                                                   const float* __restrict__ g,
                                                   const float* __restrict__ bb,
                                                   u16* __restrict__ yn) {
  int row = blockIdx.x, t = threadIdx.x;
  const float* yr = y + (size_t)row * 2048 + t * 8;
  float4 v0 = *(const float4*)(yr);
  float4 v1 = *(const float4*)(yr + 4);
  float x[8] = {v0.x, v0.y, v0.z, v0.w, v1.x, v1.y, v1.z, v1.w};
  float s = 0.f, ss = 0.f;
#pragma unroll
  for (int j = 0; j < 8; ++j) { s += x[j]; ss += x[j] * x[j]; }
#pragma unroll
  for (int off = 32; off > 0; off >>= 1) {
    s += __shfl_down(s, off);
    ss += __shfl_down(ss, off);
  }
  __shared__ float rs[4], rq[4];
  int lane = t & 63, wid = t >> 6;
  if (lane == 0) { rs[wid] = s; rq[wid] = ss; }
  __syncthreads();
  float S = rs[0] + rs[1] + rs[2] + rs[3];
  float Q = rq[0] + rq[1] + rq[2] + rq[3];
  float mean = S * (1.f / 2048.f);
  float var = Q * (1.f / 2048.f) - mean * mean;
  float rstd = rsqrtf(var + 1e-5f);
  float4 g0 = *(const float4*)(g + t * 8);
  float4 g1 = *(const float4*)(g + t * 8 + 4);
  float4 b0 = *(const float4*)(bb + t * 8);
  float4 b1 = *(const float4*)(bb + t * 8 + 4);
  float gg[8] = {g0.x, g0.y, g0.z, g0.w, g1.x, g1.y, g1.z, g1.w};
  float bv[8] = {b0.x, b0.y, b0.z, b0.w, b1.x, b1.y, b1.z, b1.w};
  uint4 ov; u16* po = (u16*)&ov;
#pragma unroll
  for (int j = 0; j < 8; ++j)
    po[j] = f2bf((x[j] - mean) * rstd * gg[j] + bv[j]);
  *(uint4*)(yn + (size_t)row * 2048 + t * 8) = ov;
}

// ================= GEMM core: 2-buffer counted-vmcnt pipeline (BK=64) =================
// Round-9/15 proven best (46.8 us O-proj). row&7 swizzle: 0 conflicts measured.
__device__ __forceinline__ void gemm_pipe(const u16* __restrict__ A,
                                          const u16* __restrict__ Bt,
                                          int K, int m0, int n0,
                                          int wm, int wn, int lr, int lg,
                                          int wid, int lane,
                                          f32x4 (&acc)[4][4]) {
  __shared__ __align__(16) u16 As[2][128 * 64];
  __shared__ __align__(16) u16 Bs[2][128 * 64];
  int sk = lr & 7;
  int srow[4], scol[4], sbase[4];
#pragma unroll
  for (int j = 0; j < 4; ++j) {
    int s0 = (wid * 4 + j) * 64;
    int s = s0 + lane;
    srow[j] = s >> 3;
    scol[j] = ((s & 7) ^ (srow[j] & 7)) * 8;
    sbase[j] = s0 * 8;
  }
  int nk = K >> 6;
#pragma unroll
  for (int pt = 0; pt < 2; ++pt)
#pragma unroll
    for (int j = 0; j < 4; ++j) {
      gl_lds16(A + (size_t)(m0 + srow[j]) * K + pt * 64 + scol[j], As[pt] + sbase[j]);
      gl_lds16(Bt + (size_t)(n0 + srow[j]) * K + pt * 64 + scol[j], Bs[pt] + sbase[j]);
    }
  for (int tt = 0; tt < nk; ++tt) {
    if (tt + 1 < nk)
      asm volatile("s_waitcnt vmcnt(8)" ::: "memory");   // oldest tile done
    else
      asm volatile("s_waitcnt vmcnt(0)" ::: "memory");
    __builtin_amdgcn_s_barrier();
    __builtin_amdgcn_sched_barrier(0);
    const u16* as = As[tt & 1];
    const u16* bs = Bs[tt & 1];
#pragma unroll
    for (int kk = 0; kk < 2; ++kk) {
      bfrag a[4], b[4];
#pragma unroll
      for (int i = 0; i < 4; ++i)
        a[i] = *(const bfrag*)(as + (wm * 64 + i * 16 + lr) * 64 + (((kk * 4 + lg) ^ sk) * 8));
#pragma unroll
      for (int j = 0; j < 4; ++j)
        b[j] = *(const bfrag*)(bs + (wn * 64 + j * 16 + lr) * 64 + (((kk * 4 + lg) ^ sk) * 8));
      __builtin_amdgcn_s_setprio(1);
#pragma unroll
      for (int i = 0; i < 4; ++i)
#pragma unroll
        for (int j = 0; j < 4; ++j)
          acc[i][j] = mfma16(a[i], b[j], acc[i][j]);
      __builtin_amdgcn_s_setprio(0);
    }
    asm volatile("s_waitcnt lgkmcnt(0)" ::: "memory");
    __builtin_amdgcn_s_barrier();
    __builtin_amdgcn_sched_barrier(0);
    if (tt + 2 < nk) {
      int k0 = (tt + 2) * 64;
#pragma unroll
      for (int j = 0; j < 4; ++j) {
        gl_lds16(A + (size_t)(m0 + srow[j]) * K + k0 + scol[j], As[tt & 1] + sbase[j]);
        gl_lds16(Bt + (size_t)(n0 + srow[j]) * K + k0 + scol[j], Bs[tt & 1] + sbase[j]);
      }
    }
  }
}

// O-proj GEMM (f32 out), unchanged from round 15.
template <bool F32OUT>
__global__ __launch_bounds__(256) void k_gemm_bt(const u16* __restrict__ A,
                                                 const u16* __restrict__ Bt,
                                                 void* __restrict__ Cv,
                                                 int M, int N, int K, float scale) {
  int t = threadIdx.x, lane = t & 63, wid = t >> 6;
  int wm = wid >> 1, wn = wid & 1;
  int bx = blockIdx.x, by = blockIdx.y;
  xcd_swizzle(bx, by);
  int m0 = by * 128, n0 = bx * 128;
  int lr = lane & 15, lg = lane >> 4;
  f32x4 acc[4][4];
#pragma unroll
  for (int i = 0; i < 4; ++i)
#pragma unroll
    for (int j = 0; j < 4; ++j) acc[i][j] = (f32x4){0.f, 0.f, 0.f, 0.f};

  gemm_pipe(A, Bt, K, m0, n0, wm, wn, lr, lg, wid, lane, acc);

#pragma unroll
  for (int i = 0; i < 4; ++i)
#pragma unroll
    for (int j = 0; j < 4; ++j) {
      int r0 = m0 + wm * 64 + i * 16 + lg * 4;
      int c0 = n0 + wn * 64 + j * 16 + lr;
#pragma unroll
      for (int r = 0; r < 4; ++r) {
        float v = scale * acc[i][j][r];
        if (F32OUT)
          ((float*)Cv)[(size_t)(r0 + r) * N + c0] = v;
        else
          ((u16*)Cv)[(size_t)(r0 + r) * N + c0] = f2bf(v);
      }
    }
}

// ================= fused Q-GEMM + KV-GEMM: one launch, 768 blocks =================
// Blocks [0,512): q = yn(8192x2048) @ wqT(1024x2048)^T * 0.125 -> qb (bf16).
// Blocks [512,768): kv = vfb(2048x1024) @ wkvT(2048x1024)^T -> Kb / pre-transposed Vtb.
// The two are independent; merging fills the KV tail into Q's scheduler slack.
// Wave-uniform branches; single gemm_pipe call site (one 64KB LDS allocation).
__global__ __launch_bounds__(256) void k_gemm_qkv(const u16* __restrict__ yn,
                                                  const u16* __restrict__ wqT,
                                                  const u16* __restrict__ vfb,
                                                  const u16* __restrict__ wkvT,
                                                  u16* __restrict__ qb,
                                                  u16* __restrict__ Kb,
                                                  u16* __restrict__ Vtb) {
  int t = threadIdx.x, lane = t & 63, wid = t >> 6;
  int wm = wid >> 1, wn = wid & 1;
  int lr = lane & 15, lg = lane >> 4;
  int bid = blockIdx.x;
  bool isQ = bid < 512;
  const u16 *A, *Bt;
  int K, m0, n0;
  if (isQ) {
    // segment-local bijective XCD swizzle, nwg=512, grid 8x64
    int swz = (bid & 7) * 64 + (bid >> 3);
    A = yn; Bt = wqT; K = 2048;
    n0 = (swz & 7) * 128;
    m0 = (swz >> 3) * 128;
  } else {
    // nwg=256, grid 16x16
    int tt = bid - 512;
    int swz = (tt & 7) * 32 + (tt >> 3);
    A = vfb; Bt = wkvT; K = 1024;
    n0 = (swz & 15) * 128;
    m0 = (swz >> 4) * 128;
  }

  f32x4 acc[4][4];
#pragma unroll
  for (int i = 0; i < 4; ++i)
#pragma unroll
    for (int j = 0; j < 4; ++j) acc[i][j] = (f32x4){0.f, 0.f, 0.f, 0.f};

  gemm_pipe(A, Bt, K, m0, n0, wm, wn, lr, lg, wid, lane, acc);

  if (isQ) {
#pragma unroll
    for (int i = 0; i < 4; ++i)
#pragma unroll
      for (int j = 0; j < 4; ++j) {
        int r0 = m0 + wm * 64 + i * 16 + lg * 4;
        int c0 = n0 + wn * 64 + j * 16 + lr;
#pragma unroll
        for (int r = 0; r < 4; ++r)
          qb[(size_t)(r0 + r) * 1024 + c0] = f2bf(0.125f * acc[i][j][r]);
      }
  } else {
#pragma unroll
    for (int i = 0; i < 4; ++i)
#pragma unroll
      for (int j = 0; j < 4; ++j) {
        int r0 = m0 + wm * 64 + i * 16 + lg * 4;
        int c0 = n0 + wn * 64 + j * 16 + lr;
        if (c0 < 1024) {
#pragma unroll
          for (int r = 0; r < 4; ++r)
            Kb[(size_t)(r0 + r) * 1024 + c0] = f2bf(acc[i][j][r]);
        } else {
          int d = c0 - 1024;
          int hh = d >> 6, dd = d & 63;
          int bq = r0 >> 9, kvp = r0 & 511;
          u16x4 pk;
#pragma unroll
          for (int r = 0; r < 4; ++r) pk[r] = f2bf(acc[i][j][r]);
          *(u16x4*)(Vtb + ((size_t)(bq * 16 + hh) * 64 + dd) * 512 + kvp) = pk;
        }
      }
  }
}

// ---------------- fused attention (swapped-QK^T, P in registers, dbuf K/V) ----------------
__global__ __launch_bounds__(256, 2) void k_attn(const u16* __restrict__ q,
                                                 const u16* __restrict__ kb,
                                                 const u16* __restrict__ vt,
                                                 u16* __restrict__ ao) {
  __shared__ __align__(16) u16 Ks[2][128 * 64];   // [kv][d], swz key row&7
  __shared__ __align__(16) u16 Vt[2][64 * 128];   // [d][kv], swz key d&7
  int t = threadIdx.x, lane = t & 63, wid = t >> 6;
  int lr = lane & 15, lg = lane >> 4;
  int sk = lr & 7;
  int a_ = lg >> 1, b_ = lg & 1;
  int bh = blockIdx.y, b = bh >> 4, h = bh & 15;
  int q0 = blockIdx.x * 128 + wid * 32;

  const u16* qg = q + (size_t)(b * 2048 + q0) * 1024 + h * 64;
  bfrag qf[2][2];
#pragma unroll
  for (int rt = 0; rt < 2; ++rt)
#pragma unroll
    for (int kk = 0; kk < 2; ++kk)
      qf[rt][kk] = *(const bfrag*)(qg + (size_t)(rt * 16 + lr) * 1024 + kk * 32 + lg * 8);

  f32x4 o[2][4];
#pragma unroll
  for (int rt = 0; rt < 2; ++rt)
#pragma unroll
    for (int dt = 0; dt < 4; ++dt) o[rt][dt] = (f32x4){0.f, 0.f, 0.f, 0.f};
  float m_s[2] = {-1e30f, -1e30f}, l_s[2] = {0.f, 0.f};

  const u16* kgb = kb + (size_t)(b * 512) * 1024 + h * 64;
  const u16* vgb = vt + (size_t)bh * 64 * 512;

  int krow[4], kcol[4], kbase[4];
#pragma unroll
  for (int j = 0; j < 4; ++j) {
    int g = wid * 4 + j;
    int s = g * 64 + lane;
    krow[j] = s >> 3;
    kcol[j] = ((s & 7) ^ (krow[j] & 7)) * 8;
    kbase[j] = g * 512;
  }

#pragma unroll
  for (int j = 0; j < 4; ++j)
    gl_lds16(kgb + (size_t)krow[j] * 1024 + kcol[j], Ks[0] + kbase[j]);
#pragma unroll
  for (int j = 0; j < 4; ++j) {
    int g = wid * 4 + j;
    int d = g * 4 + (lane >> 4);
    int p = lane & 15;
    gl_lds16(vgb + (size_t)d * 512 + ((p ^ (d & 7)) * 8), Vt[0] + g * 512);
  }
  __syncthreads();

  for (int it = 0; it < 4; ++it) {
    int cur = it & 1;
    if (it + 1 < 4) {
      int kv1 = (it + 1) * 128;
#pragma unroll
      for (int j = 0; j < 4; ++j)
        gl_lds16(kgb + (size_t)(kv1 + krow[j]) * 1024 + kcol[j], Ks[cur ^ 1] + kbase[j]);
#pragma unroll
      for (int j = 0; j < 4; ++j) {
        int g = wid * 4 + j;
        int d = g * 4 + (lane >> 4);
        int p = lane & 15;
        gl_lds16(vgb + (size_t)d * 512 + kv1 + ((p ^ (d & 7)) * 8), Vt[cur ^ 1] + g * 512);
      }
    }
    const u16* ks = Ks[cur];
    const u16* vtl = Vt[cur];

    f32x4 s[2][8];
#pragma unroll
    for (int rt = 0; rt < 2; ++rt)
#pragma unroll
      for (int ct = 0; ct < 8; ++ct) s[rt][ct] = (f32x4){0.f, 0.f, 0.f, 0.f};
    __builtin_amdgcn_s_setprio(1);
#pragma unroll
    for (int ct = 0; ct < 8; ++ct)
#pragma unroll
      for (int kk = 0; kk < 2; ++kk) {
        bfrag kf = *(const bfrag*)(ks + (ct * 16 + lr) * 64 + (((kk * 4 + lg) ^ sk) * 8));
        s[0][ct] = mfma16(kf, qf[0][kk], s[0][ct]);
        s[1][ct] = mfma16(kf, qf[1][kk], s[1][ct]);
      }
    __builtin_amdgcn_s_setprio(0);

    bfrag pf[2][4];
#pragma unroll
    for (int rt = 0; rt < 2; ++rt) {
      float mloc = -1e30f;
#pragma unroll
      for (int ct = 0; ct < 8; ++ct)
#pragma unroll
        for (int r = 0; r < 4; ++r) mloc = fmaxf(mloc, s[rt][ct][r]);
      mloc = fmaxf(mloc, __shfl_xor(mloc, 16));
      mloc = fmaxf(mloc, __shfl_xor(mloc, 32));
      float mn = fmaxf(m_s[rt], mloc);
      float scq = __expf(m_s[rt] - mn);
      float ps = 0.f;
#pragma unroll
      for (int ct = 0; ct < 8; ++ct)
#pragma unroll
        for (int r = 0; r < 4; ++r) {
          float p = __expf(s[rt][ct][r] - mn);
          s[rt][ct][r] = p;
          ps += p;
        }
      ps += __shfl_xor(ps, 16);
      ps += __shfl_xor(ps, 32);
      l_s[rt] = l_s[rt] * scq + ps;
      m_s[rt] = mn;
      float sc4[4];
#pragma unroll
      for (int r = 0; r < 4; ++r) sc4[r] = __shfl(scq, (lane & 48) | (lg * 4 + r));
#pragma unroll
      for (int dt = 0; dt < 4; ++dt)
#pragma unroll
        for (int r = 0; r < 4; ++r) o[rt][dt][r] *= sc4[r];

      unsigned w0[8], w1[8];
#pragma unroll
      for (int ct = 0; ct < 8; ++ct) {
        w0[ct] = packbf(s[rt][ct][0], s[rt][ct][1]);
        w1[ct] = packbf(s[rt][ct][2], s[rt][ct][3]);
      }
#pragma unroll
      for (int kt = 0; kt < 4; ++kt) {
        unsigned c0w0 = w0[2 * kt], c0w1 = w1[2 * kt];
        unsigned c1w0 = w0[2 * kt + 1], c1w1 = w1[2 * kt + 1];
        unsigned s0 = a_ ? c0w0 : c1w0;
        unsigned s1 = a_ ? c0w1 : c1w1;
        unsigned k0 = a_ ? c1w0 : c0w0;
        unsigned k1 = a_ ? c1w1 : c0w1;
        unsigned r0 = (unsigned)__shfl_xor((int)s0, 32);
        unsigned r1 = (unsigned)__shfl_xor((int)s1, 32);
        unsigned x0 = (a_ == b_) ? r0 : k0;
        unsigned x1 = (a_ == b_) ? r1 : k1;
        unsigned kk0 = (a_ == b_) ? k0 : r0;
        unsigned kk1 = (a_ == b_) ? k1 : r1;
        unsigned q0_ = (unsigned)__shfl_xor((int)x0, 16);
        unsigned q1_ = (unsigned)__shfl_xor((int)x1, 16);
        union { unsigned u[4]; bfrag f; } uf;
        uf.u[0] = b_ ? q0_ : kk0;
        uf.u[1] = b_ ? q1_ : kk1;
        uf.u[2] = b_ ? kk0 : q0_;
        uf.u[3] = b_ ? kk1 : q1_;
        pf[rt][kt] = uf.f;
      }
    }

    __builtin_amdgcn_s_setprio(1);
#pragma unroll
    for (int dt = 0; dt < 4; ++dt)
#pragma unroll
      for (int kt = 0; kt < 4; ++kt) {
        int d = dt * 16 + lr;
        bfrag vfb2 = *(const bfrag*)(vtl + d * 128 + (((kt * 4 + lg) ^ (d & 7)) * 8));
        o[0][dt] = mfma16(pf[0][kt], vfb2, o[0][dt]);
        o[1][dt] = mfma16(pf[1][kt], vfb2, o[1][dt]);
      }
    __builtin_amdgcn_s_setprio(0);

    if (it + 1 < 4) __syncthreads();
  }

#pragma unroll
  for (int rt = 0; rt < 2; ++rt) {
    float invq = 1.f / l_s[rt];
    float i4[4];
#pragma unroll
    for (int r = 0; r < 4; ++r) i4[r] = __shfl(invq, (lane & 48) | (lg * 4 + r));
#pragma unroll
    for (int dt = 0; dt < 4; ++dt)
#pragma unroll
      for (int r = 0; r < 4; ++r)
        ao[(size_t)(b * 2048 + q0 + rt * 16 + lg * 4 + r) * 1024 + h * 64 + dt * 16 + lr] =
            f2bf(o[rt][dt][r] * i4[r]);
  }
}

extern "C" void kernel_launch(void* const* d_in, const int* in_sizes, int n_in,
                              void* d_out, int out_size, void* d_ws, size_t ws_size,
                              hipStream_t stream) {
  const float* y   = (const float*)d_in[0];
  const float* vf  = (const float*)d_in[1];
  const float* g   = (const float*)d_in[2];
  const float* bb  = (const float*)d_in[3];
  const float* Wq  = (const float*)d_in[4];
  const float* Wkv = (const float*)d_in[5];
  const float* Wo  = (const float*)d_in[6];
  float* out = (float*)d_out;
  char* ws = (char*)d_ws;

  u16* qb   = (u16*)(ws + 0ull);          // 8192x1024  (16 MB)
  u16* kbuf = (u16*)(ws + 16777216ull);   // 2048x1024  ( 4 MB) K
  u16* vtb  = (u16*)(ws + 20971520ull);   // 64*64x512  ( 4 MB) V^T per (b,h)
  u16* aob  = (u16*)(ws + 25165824ull);   // 8192x1024  (16 MB)
  u16* wqT  = (u16*)(ws + 41943040ull);   // 1024x2048  ( 4 MB)
  u16* wkvT = (u16*)(ws + 46137344ull);   // 2048x1024  ( 4 MB)
  u16* woT  = (u16*)(ws + 50331648ull);   // 2048x1024  ( 4 MB)
  u16* vfb  = (u16*)(ws + 54525952ull);   // 2048x1024  ( 4 MB)
  // yn (8192x2048 bf16 = 32 MB) lives in d_out; consumed by Q-GEMM, then d_out
  // is fully overwritten by the final GEMM. Deterministic across replays.
  u16* yn = (u16*)d_out;

  dim3 tb(32, 8, 1);
  // all three weight transposes in one launch (3 x 2048 tiles)
  k_transpose3<<<6144, tb, 0, stream>>>(Wq, Wkv, Wo, wqT, wkvT, woT);
  k_cast<<<(2048 * 1024 / 8 + 255) / 256, 256, 0, stream>>>(vf, vfb, 2048 * 1024 / 8);
  k_layernorm<<<8192, 256, 0, stream>>>(y, g, bb, yn);
  // fused: q = LN(y) @ Wq * 0.125  AND  kv = vis @ Wkv (K + pre-transposed V)
  k_gemm_qkv<<<768, 256, 0, stream>>>(yn, wqT, vfb, wkvT, qb, kbuf, vtb);
  k_attn<<<dim3(16, 64, 1), 256, 0, stream>>>(qb, kbuf, vtb, aob);
  // out = ao @ Wo (f32 out)
  k_gemm_bt<true><<<dim3(2048 / 128, 8192 / 128, 1), 256, 0, stream>>>(aob, woT, out, 8192, 2048, 1024, 1.0f);
}

// Round 17
// 167.510 us; speedup vs baseline: 1.0228x; 1.0228x over previous
//
#include <hip/hip_runtime.h>
#include <stdint.h>

typedef unsigned short u16;
typedef __bf16 bfrag __attribute__((ext_vector_type(8)));   // 8 x bf16 = 4 VGPRs (MFMA A/B frag)
typedef float f32x4 __attribute__((ext_vector_type(4)));    // MFMA C/D frag
typedef u16 u16x4 __attribute__((ext_vector_type(4)));

__device__ __forceinline__ float bf2f(u16 u) {
  union { unsigned i; float f; } x; x.i = ((unsigned)u) << 16; return x.f;
}
__device__ __forceinline__ u16 f2bf(float f) {
  union { unsigned i; float f; } x; x.f = f;
  unsigned r = x.i + 0x7fffu + ((x.i >> 16) & 1u);   // RNE
  return (u16)(r >> 16);
}
// pure-C bf16 pair pack (inline-asm cvt_pk was implicated in the round-5 failure)
__device__ __forceinline__ unsigned packbf(float lo, float hi) {
  return (unsigned)f2bf(lo) | ((unsigned)f2bf(hi) << 16);
}

__device__ __forceinline__ f32x4 mfma16(bfrag a, bfrag b, f32x4 c) {
  return __builtin_amdgcn_mfma_f32_16x16x32_bf16(a, b, c, 0, 0, 0);
}

// async global->LDS, 16B per lane. LDS dest = wave-uniform base + lane*16.
__device__ __forceinline__ void gl_lds16(const u16* g, const u16* l) {
  __builtin_amdgcn_global_load_lds(
      (const __attribute__((address_space(1))) unsigned int*)g,
      (__attribute__((address_space(3))) unsigned int*)l, 16, 0, 0);
}

// XCD-bijective block swizzle (nwg must be a multiple of 8 — all our grids are).
__device__ __forceinline__ void xcd_swizzle(int& bx, int& by) {
  int gx = gridDim.x, nwg = gx * gridDim.y;
  int flat = by * gx + bx;
  int cpx = nwg >> 3;
  int swz = (flat & 7) * cpx + (flat >> 3);
  bx = swz % gx;
  by = swz / gx;
}

// ---------------- fused weight transposes: 3 segments, one launch ----------------
// seg0: Wq (2048x1024) -> wqT (1024x2048); seg1: Wkv (1024x2048) -> wkvT;
// seg2: Wo (1024x2048) -> woT. Identical tile body; wave-uniform segment decode.
__global__ __launch_bounds__(256) void k_transpose3(const float* __restrict__ i0,
                                                    const float* __restrict__ i1,
                                                    const float* __restrict__ i2,
                                                    u16* __restrict__ o0,
                                                    u16* __restrict__ o1,
                                                    u16* __restrict__ o2) {
  __shared__ u16 tile[32][33];
  int bid = blockIdx.x;
  int seg = bid >> 11, tt = bid & 2047;   // 2048 tiles per segment
  const float* in;
  u16* out;
  int R, C, bx, by;
  if (seg == 0)      { in = i0; out = o0; R = 2048; C = 1024; bx = tt & 31; by = tt >> 5; }
  else if (seg == 1) { in = i1; out = o1; R = 1024; C = 2048; bx = tt & 63; by = tt >> 6; }
  else               { in = i2; out = o2; R = 1024; C = 2048; bx = tt & 63; by = tt >> 6; }
  int c0 = bx * 32, r0 = by * 32;
  int tx = threadIdx.x, ty = threadIdx.y;   // (32,8)
#pragma unroll
  for (int i = 0; i < 4; ++i)
    tile[ty + i * 8][tx] = f2bf(in[(size_t)(r0 + ty + i * 8) * C + c0 + tx]);
  __syncthreads();
#pragma unroll
  for (int i = 0; i < 4; ++i)
    out[(size_t)(c0 + ty + i * 8) * R + r0 + tx] = tile[tx][ty + i * 8];
}

// ---------------- cast f32 -> bf16, 8 elems/thread ----------------
__global__ __launch_bounds__(256) void k_cast(const float* __restrict__ in,
                                              u16* __restrict__ out, int n8) {
  int i = blockIdx.x * 256 + threadIdx.x;
  if (i >= n8) return;
  float4 a = *(const float4*)(in + (size_t)i * 8);
  float4 b = *(const float4*)(in + (size_t)i * 8 + 4);
  uint4 ov; u16* po = (u16*)&ov;
  po[0] = f2bf(a.x); po[1] = f2bf(a.y); po[2] = f2bf(a.z); po[3] = f2bf(a.w);
  po[4] = f2bf(b.x); po[5] = f2bf(b.y); po[6] = f2bf(b.z); po[7] = f2bf(b.w);
  *(uint4*)(out + (size_t)i * 8) = ov;
}

// ---------------- LayerNorm over last dim (2048), f32 in -> bf16 out ----------------
__global__ __launch_bounds__(256) void k_layernorm(const float* __restrict__ y,
                                                   const float* __restrict__ g,
                                                   const float* __restrict__ bb,
                                                   u16* __restrict__ yn) {
  int row = blockIdx.x, t = threadIdx.x;
  const float* yr = y + (size_t)row * 2048 + t * 8;
  float4 v0 = *(const float4*)(yr);
  float4 v1 = *(const float4*)(yr + 4);
  float x[8] = {v0.x, v0.y, v0.z, v0.w, v1.x, v1.y, v1.z, v1.w};
  float s = 0.f, ss = 0.f;
#pragma unroll
  for (int j = 0; j < 8; ++j) { s += x[j]; ss += x[j] * x[j]; }
#pragma unroll
  for (int off = 32; off > 0; off >>= 1) {
    s += __shfl_down(s, off);
    ss += __shfl_down(ss, off);
  }
  __shared__ float rs[4], rq[4];
  int lane = t & 63, wid = t >> 6;
  if (lane == 0) { rs[wid] = s; rq[wid] = ss; }
  __syncthreads();
  float S = rs[0] + rs[1] + rs[2] + rs[3];
  float Q = rq[0] + rq[1] + rq[2] + rq[3];
  float mean = S * (1.f / 2048.f);
  float var = Q * (1.f / 2048.f) - mean * mean;
  float rstd = rsqrtf(var + 1e-5f);
  float4 g0 = *(const float4*)(g + t * 8);
  float4 g1 = *(const float4*)(g + t * 8 + 4);
  float4 b0 = *(const float4*)(bb + t * 8);
  float4 b1 = *(const float4*)(bb + t * 8 + 4);
  float gg[8] = {g0.x, g0.y, g0.z, g0.w, g1.x, g1.y, g1.z, g1.w};
  float bv[8] = {b0.x, b0.y, b0.z, b0.w, b1.x, b1.y, b1.z, b1.w};
  uint4 ov; u16* po = (u16*)&ov;
#pragma unroll
  for (int j = 0; j < 8; ++j)
    po[j] = f2bf((x[j] - mean) * rstd * gg[j] + bv[j]);
  *(uint4*)(yn + (size_t)row * 2048 + t * 8) = ov;
}

// ================= GEMM core: 2-buffer counted-vmcnt pipeline (BK=64) =================
// Round-9/15 proven best (46.8 us O-proj): per iter s_waitcnt vmcnt(8) [oldest tile's 8
// calls done; younger tile's 8 stay in flight] -> s_barrier -> ds_read+MFMA ->
// lgkmcnt(0) -> s_barrier -> stage(t+2). row&7 swizzle: 0 conflicts measured.
__device__ __forceinline__ void gemm_pipe(const u16* __restrict__ A,
                                          const u16* __restrict__ Bt,
                                          int K, int m0, int n0,
                                          int wm, int wn, int lr, int lg,
                                          int wid, int lane,
                                          f32x4 (&acc)[4][4]) {
  __shared__ __align__(16) u16 As[2][128 * 64];
  __shared__ __align__(16) u16 Bs[2][128 * 64];
  int sk = lr & 7;
  int srow[4], scol[4], sbase[4];
#pragma unroll
  for (int j = 0; j < 4; ++j) {
    int s0 = (wid * 4 + j) * 64;
    int s = s0 + lane;
    srow[j] = s >> 3;
    scol[j] = ((s & 7) ^ (srow[j] & 7)) * 8;
    sbase[j] = s0 * 8;
  }
  int nk = K >> 6;
#pragma unroll
  for (int pt = 0; pt < 2; ++pt)
#pragma unroll
    for (int j = 0; j < 4; ++j) {
      gl_lds16(A + (size_t)(m0 + srow[j]) * K + pt * 64 + scol[j], As[pt] + sbase[j]);
      gl_lds16(Bt + (size_t)(n0 + srow[j]) * K + pt * 64 + scol[j], Bs[pt] + sbase[j]);
    }
  for (int tt = 0; tt < nk; ++tt) {
    if (tt + 1 < nk)
      asm volatile("s_waitcnt vmcnt(8)" ::: "memory");   // oldest tile done
    else
      asm volatile("s_waitcnt vmcnt(0)" ::: "memory");
    __builtin_amdgcn_s_barrier();
    __builtin_amdgcn_sched_barrier(0);
    const u16* as = As[tt & 1];
    const u16* bs = Bs[tt & 1];
#pragma unroll
    for (int kk = 0; kk < 2; ++kk) {
      bfrag a[4], b[4];
#pragma unroll
      for (int i = 0; i < 4; ++i)
        a[i] = *(const bfrag*)(as + (wm * 64 + i * 16 + lr) * 64 + (((kk * 4 + lg) ^ sk) * 8));
#pragma unroll
      for (int j = 0; j < 4; ++j)
        b[j] = *(const bfrag*)(bs + (wn * 64 + j * 16 + lr) * 64 + (((kk * 4 + lg) ^ sk) * 8));
      __builtin_amdgcn_s_setprio(1);
#pragma unroll
      for (int i = 0; i < 4; ++i)
#pragma unroll
        for (int j = 0; j < 4; ++j)
          acc[i][j] = mfma16(a[i], b[j], acc[i][j]);
      __builtin_amdgcn_s_setprio(0);
    }
    asm volatile("s_waitcnt lgkmcnt(0)" ::: "memory");
    __builtin_amdgcn_s_barrier();
    __builtin_amdgcn_sched_barrier(0);
    if (tt + 2 < nk) {
      int k0 = (tt + 2) * 64;
#pragma unroll
      for (int j = 0; j < 4; ++j) {
        gl_lds16(A + (size_t)(m0 + srow[j]) * K + k0 + scol[j], As[tt & 1] + sbase[j]);
        gl_lds16(Bt + (size_t)(n0 + srow[j]) * K + k0 + scol[j], Bs[tt & 1] + sbase[j]);
      }
    }
  }
}

template <bool F32OUT>
__global__ __launch_bounds__(256) void k_gemm_bt(const u16* __restrict__ A,
                                                 const u16* __restrict__ Bt,
                                                 void* __restrict__ Cv,
                                                 int M, int N, int K, float scale) {
  int t = threadIdx.x, lane = t & 63, wid = t >> 6;
  int wm = wid >> 1, wn = wid & 1;
  int bx = blockIdx.x, by = blockIdx.y;
  xcd_swizzle(bx, by);
  int m0 = by * 128, n0 = bx * 128;
  int lr = lane & 15, lg = lane >> 4;
  f32x4 acc[4][4];
#pragma unroll
  for (int i = 0; i < 4; ++i)
#pragma unroll
    for (int j = 0; j < 4; ++j) acc[i][j] = (f32x4){0.f, 0.f, 0.f, 0.f};

  gemm_pipe(A, Bt, K, m0, n0, wm, wn, lr, lg, wid, lane, acc);

#pragma unroll
  for (int i = 0; i < 4; ++i)
#pragma unroll
    for (int j = 0; j < 4; ++j) {
      int r0 = m0 + wm * 64 + i * 16 + lg * 4;
      int c0 = n0 + wn * 64 + j * 16 + lr;
#pragma unroll
      for (int r = 0; r < 4; ++r) {
        float v = scale * acc[i][j][r];
        if (F32OUT)
          ((float*)Cv)[(size_t)(r0 + r) * N + c0] = v;
        else
          ((u16*)Cv)[(size_t)(r0 + r) * N + c0] = f2bf(v);
      }
    }
}

// KV GEMM: K=1024; cols [0,1024) -> Kb; cols [1024,2048): V pre-transposed into
// vtb[(b*16+h)*64 + d][512] (packed 8B stores).
__global__ __launch_bounds__(256) void k_gemm_kv(const u16* __restrict__ A,
                                                 const u16* __restrict__ Bt,
                                                 u16* __restrict__ Kb,
                                                 u16* __restrict__ Vtb) {
  const int K = 1024;
  int t = threadIdx.x, lane = t & 63, wid = t >> 6;
  int wm = wid >> 1, wn = wid & 1;
  int bx = blockIdx.x, by = blockIdx.y;
  xcd_swizzle(bx, by);
  int m0 = by * 128, n0 = bx * 128;
  int lr = lane & 15, lg = lane >> 4;
  f32x4 acc[4][4];
#pragma unroll
  for (int i = 0; i < 4; ++i)
#pragma unroll
    for (int j = 0; j < 4; ++j) acc[i][j] = (f32x4){0.f, 0.f, 0.f, 0.f};

  gemm_pipe(A, Bt, K, m0, n0, wm, wn, lr, lg, wid, lane, acc);

#pragma unroll
  for (int i = 0; i < 4; ++i)
#pragma unroll
    for (int j = 0; j < 4; ++j) {
      int r0 = m0 + wm * 64 + i * 16 + lg * 4;
      int c0 = n0 + wn * 64 + j * 16 + lr;
      if (c0 < 1024) {
#pragma unroll
        for (int r = 0; r < 4; ++r)
          Kb[(size_t)(r0 + r) * 1024 + c0] = f2bf(acc[i][j][r]);
      } else {
        int d = c0 - 1024;
        int hh = d >> 6, dd = d & 63;
        int bq = r0 >> 9, kvp = r0 & 511;
        u16x4 pk;
#pragma unroll
        for (int r = 0; r < 4; ++r) pk[r] = f2bf(acc[i][j][r]);
        *(u16x4*)(Vtb + ((size_t)(bq * 16 + hh) * 64 + dd) * 512 + kvp) = pk;
      }
    }
}

// ---------------- fused attention (swapped-QK^T, P in registers, dbuf K/V) ----------------
// grid: (16 q-chunks of 128, 64 = b*16+h). 4 waves, each wave 32 q-rows. KVBLK=128.
// kf/vfb LDS fragment loads hoisted out of the rt loop; setprio on MFMA clusters.
__global__ __launch_bounds__(256, 2) void k_attn(const u16* __restrict__ q,
                                                 const u16* __restrict__ kb,
                                                 const u16* __restrict__ vt,
                                                 u16* __restrict__ ao) {
  __shared__ __align__(16) u16 Ks[2][128 * 64];   // [kv][d], swz key row&7
  __shared__ __align__(16) u16 Vt[2][64 * 128];   // [d][kv], swz key d&7
  int t = threadIdx.x, lane = t & 63, wid = t >> 6;
  int lr = lane & 15, lg = lane >> 4;
  int sk = lr & 7;
  int a_ = lg >> 1, b_ = lg & 1;
  int bh = blockIdx.y, b = bh >> 4, h = bh & 15;
  int q0 = blockIdx.x * 128 + wid * 32;

  const u16* qg = q + (size_t)(b * 2048 + q0) * 1024 + h * 64;
  bfrag qf[2][2];
#pragma unroll
  for (int rt = 0; rt < 2; ++rt)
#pragma unroll
    for (int kk = 0; kk < 2; ++kk)
      qf[rt][kk] = *(const bfrag*)(qg + (size_t)(rt * 16 + lr) * 1024 + kk * 32 + lg * 8);

  f32x4 o[2][4];
#pragma unroll
  for (int rt = 0; rt < 2; ++rt)
#pragma unroll
    for (int dt = 0; dt < 4; ++dt) o[rt][dt] = (f32x4){0.f, 0.f, 0.f, 0.f};
  float m_s[2] = {-1e30f, -1e30f}, l_s[2] = {0.f, 0.f};

  const u16* kgb = kb + (size_t)(b * 512) * 1024 + h * 64;
  const u16* vgb = vt + (size_t)bh * 64 * 512;

  int krow[4], kcol[4], kbase[4];
#pragma unroll
  for (int j = 0; j < 4; ++j) {
    int g = wid * 4 + j;
    int s = g * 64 + lane;
    krow[j] = s >> 3;
    kcol[j] = ((s & 7) ^ (krow[j] & 7)) * 8;
    kbase[j] = g * 512;
  }

#pragma unroll
  for (int j = 0; j < 4; ++j)
    gl_lds16(kgb + (size_t)krow[j] * 1024 + kcol[j], Ks[0] + kbase[j]);
#pragma unroll
  for (int j = 0; j < 4; ++j) {
    int g = wid * 4 + j;
    int d = g * 4 + (lane >> 4);
    int p = lane & 15;
    gl_lds16(vgb + (size_t)d * 512 + ((p ^ (d & 7)) * 8), Vt[0] + g * 512);
  }
  __syncthreads();

  for (int it = 0; it < 4; ++it) {
    int cur = it & 1;
    if (it + 1 < 4) {
      int kv1 = (it + 1) * 128;
#pragma unroll
      for (int j = 0; j < 4; ++j)
        gl_lds16(kgb + (size_t)(kv1 + krow[j]) * 1024 + kcol[j], Ks[cur ^ 1] + kbase[j]);
#pragma unroll
      for (int j = 0; j < 4; ++j) {
        int g = wid * 4 + j;
        int d = g * 4 + (lane >> 4);
        int p = lane & 15;
        gl_lds16(vgb + (size_t)d * 512 + kv1 + ((p ^ (d & 7)) * 8), Vt[cur ^ 1] + g * 512);
      }
    }
    const u16* ks = Ks[cur];
    const u16* vtl = Vt[cur];

    f32x4 s[2][8];
#pragma unroll
    for (int rt = 0; rt < 2; ++rt)
#pragma unroll
      for (int ct = 0; ct < 8; ++ct) s[rt][ct] = (f32x4){0.f, 0.f, 0.f, 0.f};
    __builtin_amdgcn_s_setprio(1);
#pragma unroll
    for (int ct = 0; ct < 8; ++ct)
#pragma unroll
      for (int kk = 0; kk < 2; ++kk) {
        bfrag kf = *(const bfrag*)(ks + (ct * 16 + lr) * 64 + (((kk * 4 + lg) ^ sk) * 8));
        s[0][ct] = mfma16(kf, qf[0][kk], s[0][ct]);
        s[1][ct] = mfma16(kf, qf[1][kk], s[1][ct]);
      }
    __builtin_amdgcn_s_setprio(0);

    bfrag pf[2][4];
#pragma unroll
    for (int rt = 0; rt < 2; ++rt) {
      float mloc = -1e30f;
#pragma unroll
      for (int ct = 0; ct < 8; ++ct)
#pragma unroll
        for (int r = 0; r < 4; ++r) mloc = fmaxf(mloc, s[rt][ct][r]);
      mloc = fmaxf(mloc, __shfl_xor(mloc, 16));
      mloc = fmaxf(mloc, __shfl_xor(mloc, 32));
      float mn = fmaxf(m_s[rt], mloc);
      float scq = __expf(m_s[rt] - mn);
      float ps = 0.f;
#pragma unroll
      for (int ct = 0; ct < 8; ++ct)
#pragma unroll
        for (int r = 0; r < 4; ++r) {
          float p = __expf(s[rt][ct][r] - mn);
          s[rt][ct][r] = p;
          ps += p;
        }
      ps += __shfl_xor(ps, 16);
      ps += __shfl_xor(ps, 32);
      l_s[rt] = l_s[rt] * scq + ps;
      m_s[rt] = mn;
      float sc4[4];
#pragma unroll
      for (int r = 0; r < 4; ++r) sc4[r] = __shfl(scq, (lane & 48) | (lg * 4 + r));
#pragma unroll
      for (int dt = 0; dt < 4; ++dt)
#pragma unroll
        for (int r = 0; r < 4; ++r) o[rt][dt][r] *= sc4[r];

      unsigned w0[8], w1[8];
#pragma unroll
      for (int ct = 0; ct < 8; ++ct) {
        w0[ct] = packbf(s[rt][ct][0], s[rt][ct][1]);
        w1[ct] = packbf(s[rt][ct][2], s[rt][ct][3]);
      }
#pragma unroll
      for (int kt = 0; kt < 4; ++kt) {
        unsigned c0w0 = w0[2 * kt], c0w1 = w1[2 * kt];
        unsigned c1w0 = w0[2 * kt + 1], c1w1 = w1[2 * kt + 1];
        unsigned s0 = a_ ? c0w0 : c1w0;
        unsigned s1 = a_ ? c0w1 : c1w1;
        unsigned k0 = a_ ? c1w0 : c0w0;
        unsigned k1 = a_ ? c1w1 : c0w1;
        unsigned r0 = (unsigned)__shfl_xor((int)s0, 32);
        unsigned r1 = (unsigned)__shfl_xor((int)s1, 32);
        unsigned x0 = (a_ == b_) ? r0 : k0;
        unsigned x1 = (a_ == b_) ? r1 : k1;
        unsigned kk0 = (a_ == b_) ? k0 : r0;
        unsigned kk1 = (a_ == b_) ? k1 : r1;
        unsigned q0_ = (unsigned)__shfl_xor((int)x0, 16);
        unsigned q1_ = (unsigned)__shfl_xor((int)x1, 16);
        union { unsigned u[4]; bfrag f; } uf;
        uf.u[0] = b_ ? q0_ : kk0;
        uf.u[1] = b_ ? q1_ : kk1;
        uf.u[2] = b_ ? kk0 : q0_;
        uf.u[3] = b_ ? kk1 : q1_;
        pf[rt][kt] = uf.f;
      }
    }

    __builtin_amdgcn_s_setprio(1);
#pragma unroll
    for (int dt = 0; dt < 4; ++dt)
#pragma unroll
      for (int kt = 0; kt < 4; ++kt) {
        int d = dt * 16 + lr;
        bfrag vfb = *(const bfrag*)(vtl + d * 128 + (((kt * 4 + lg) ^ (d & 7)) * 8));
        o[0][dt] = mfma16(pf[0][kt], vfb, o[0][dt]);
        o[1][dt] = mfma16(pf[1][kt], vfb, o[1][dt]);
      }
    __builtin_amdgcn_s_setprio(0);

    if (it + 1 < 4) __syncthreads();
  }

#pragma unroll
  for (int rt = 0; rt < 2; ++rt) {
    float invq = 1.f / l_s[rt];
    float i4[4];
#pragma unroll
    for (int r = 0; r < 4; ++r) i4[r] = __shfl(invq, (lane & 48) | (lg * 4 + r));
#pragma unroll
    for (int dt = 0; dt < 4; ++dt)
#pragma unroll
      for (int r = 0; r < 4; ++r)
        ao[(size_t)(b * 2048 + q0 + rt * 16 + lg * 4 + r) * 1024 + h * 64 + dt * 16 + lr] =
            f2bf(o[rt][dt][r] * i4[r]);
  }
}

extern "C" void kernel_launch(void* const* d_in, const int* in_sizes, int n_in,
                              void* d_out, int out_size, void* d_ws, size_t ws_size,
                              hipStream_t stream) {
  const float* y   = (const float*)d_in[0];
  const float* vf  = (const float*)d_in[1];
  const float* g   = (const float*)d_in[2];
  const float* bb  = (const float*)d_in[3];
  const float* Wq  = (const float*)d_in[4];
  const float* Wkv = (const float*)d_in[5];
  const float* Wo  = (const float*)d_in[6];
  float* out = (float*)d_out;
  char* ws = (char*)d_ws;

  u16* qb   = (u16*)(ws + 0ull);          // 8192x1024  (16 MB)
  u16* kbuf = (u16*)(ws + 16777216ull);   // 2048x1024  ( 4 MB) K
  u16* vtb  = (u16*)(ws + 20971520ull);   // 64*64x512  ( 4 MB) V^T per (b,h)
  u16* aob  = (u16*)(ws + 25165824ull);   // 8192x1024  (16 MB)
  u16* wqT  = (u16*)(ws + 41943040ull);   // 1024x2048  ( 4 MB)
  u16* wkvT = (u16*)(ws + 46137344ull);   // 2048x1024  ( 4 MB)
  u16* woT  = (u16*)(ws + 50331648ull);   // 2048x1024  ( 4 MB)
  u16* vfb  = (u16*)(ws + 54525952ull);   // 2048x1024  ( 4 MB)
  // yn (8192x2048 bf16 = 32 MB) lives in d_out; consumed by Q-GEMM, then d_out
  // is fully overwritten by the final GEMM. Deterministic across replays.
  u16* yn = (u16*)d_out;

  dim3 tb(32, 8, 1);
  // all three weight transposes in one launch (3 x 2048 tiles)
  k_transpose3<<<6144, tb, 0, stream>>>(Wq, Wkv, Wo, wqT, wkvT, woT);
  k_cast<<<(2048 * 1024 / 8 + 255) / 256, 256, 0, stream>>>(vf, vfb, 2048 * 1024 / 8);
  k_layernorm<<<8192, 256, 0, stream>>>(y, g, bb, yn);
  // q = LN(y) @ Wq * 1/sqrt(64)
  k_gemm_bt<false><<<dim3(1024 / 128, 8192 / 128, 1), 256, 0, stream>>>(yn, wqT, qb, 8192, 1024, 2048, 0.125f);
  // kv = vis @ Wkv, split into K and pre-transposed V
  k_gemm_kv<<<dim3(2048 / 128, 2048 / 128, 1), 256, 0, stream>>>(vfb, wkvT, kbuf, vtb);
  k_attn<<<dim3(16, 64, 1), 256, 0, stream>>>(qb, kbuf, vtb, aob);
  // out = ao @ Wo (f32 out)
  k_gemm_bt<true><<<dim3(2048 / 128, 8192 / 128, 1), 256, 0, stream>>>(aob, woT, out, 8192, 2048, 1024, 1.0f);
}

// Round 18
// 162.978 us; speedup vs baseline: 1.0512x; 1.0278x over previous
//
#include <hip/hip_runtime.h>
#include <stdint.h>

typedef unsigned short u16;
typedef __bf16 bfrag __attribute__((ext_vector_type(8)));   // 8 x bf16 = 4 VGPRs (MFMA A/B frag)
typedef float f32x4 __attribute__((ext_vector_type(4)));    // MFMA C/D frag
typedef u16 u16x4 __attribute__((ext_vector_type(4)));

__device__ __forceinline__ float bf2f(u16 u) {
  union { unsigned i; float f; } x; x.i = ((unsigned)u) << 16; return x.f;
}
__device__ __forceinline__ u16 f2bf(float f) {
  union { unsigned i; float f; } x; x.f = f;
  unsigned r = x.i + 0x7fffu + ((x.i >> 16) & 1u);   // RNE
  return (u16)(r >> 16);
}
// pure-C bf16 pair pack (inline-asm cvt_pk was implicated in the round-5 failure)
__device__ __forceinline__ unsigned packbf(float lo, float hi) {
  return (unsigned)f2bf(lo) | ((unsigned)f2bf(hi) << 16);
}

__device__ __forceinline__ f32x4 mfma16(bfrag a, bfrag b, f32x4 c) {
  return __builtin_amdgcn_mfma_f32_16x16x32_bf16(a, b, c, 0, 0, 0);
}

// async global->LDS, 16B per lane. LDS dest = wave-uniform base + lane*16.
__device__ __forceinline__ void gl_lds16(const u16* g, const u16* l) {
  __builtin_amdgcn_global_load_lds(
      (const __attribute__((address_space(1))) unsigned int*)g,
      (__attribute__((address_space(3))) unsigned int*)l, 16, 0, 0);
}

// XCD-bijective block swizzle (nwg must be a multiple of 8 — all our grids are).
__device__ __forceinline__ void xcd_swizzle(int& bx, int& by) {
  int gx = gridDim.x, nwg = gx * gridDim.y;
  int flat = by * gx + bx;
  int cpx = nwg >> 3;
  int swz = (flat & 7) * cpx + (flat >> 3);
  bx = swz % gx;
  by = swz / gx;
}

// ================= fused preamble: weight transposes + vf cast + LayerNorm =================
// Blocks [0,6144): 3x weight transpose (32x32 tiles, 2048 tiles/seg).
// Blocks [6144,14336): LayerNorm rows (8192).
// Blocks [14336,15360): vf f32->bf16 cast (1024 blocks x 2048 elems).
// All segments independent; block-uniform branches; outputs consumed by later kernels.
__global__ __launch_bounds__(256) void k_pre(const float* __restrict__ Wq,
                                             const float* __restrict__ Wkv,
                                             const float* __restrict__ Wo,
                                             u16* __restrict__ wqT,
                                             u16* __restrict__ wkvT,
                                             u16* __restrict__ woT,
                                             const float* __restrict__ y,
                                             const float* __restrict__ g,
                                             const float* __restrict__ bb,
                                             u16* __restrict__ yn,
                                             const float* __restrict__ vf,
                                             u16* __restrict__ vfb) {
  __shared__ u16 tile[32][33];
  __shared__ float rs[4], rq[4];
  int bid = blockIdx.x;
  int t = threadIdx.x;

  if (bid < 6144) {
    // ---- weight transpose: in (R x C) f32 -> out (C x R) bf16 ----
    int seg = bid >> 11, tt = bid & 2047;
    const float* in;
    u16* out;
    int R, C, bx, by;
    if (seg == 0)      { in = Wq;  out = wqT;  R = 2048; C = 1024; bx = tt & 31; by = tt >> 5; }
    else if (seg == 1) { in = Wkv; out = wkvT; R = 1024; C = 2048; bx = tt & 63; by = tt >> 6; }
    else               { in = Wo;  out = woT;  R = 1024; C = 2048; bx = tt & 63; by = tt >> 6; }
    int c0 = bx * 32, r0 = by * 32;
    int tx = t & 31, ty = t >> 5;   // flat 256 -> (32,8)
#pragma unroll
    for (int i = 0; i < 4; ++i)
      tile[ty + i * 8][tx] = f2bf(in[(size_t)(r0 + ty + i * 8) * C + c0 + tx]);
    __syncthreads();
#pragma unroll
    for (int i = 0; i < 4; ++i)
      out[(size_t)(c0 + ty + i * 8) * R + r0 + tx] = tile[tx][ty + i * 8];
  } else if (bid < 14336) {
    // ---- LayerNorm over last dim (2048), f32 in -> bf16 out ----
    int row = bid - 6144;
    const float* yr = y + (size_t)row * 2048 + t * 8;
    float4 v0 = *(const float4*)(yr);
    float4 v1 = *(const float4*)(yr + 4);
    float x[8] = {v0.x, v0.y, v0.z, v0.w, v1.x, v1.y, v1.z, v1.w};
    float s = 0.f, ss = 0.f;
#pragma unroll
    for (int j = 0; j < 8; ++j) { s += x[j]; ss += x[j] * x[j]; }
#pragma unroll
    for (int off = 32; off > 0; off >>= 1) {
      s += __shfl_down(s, off);
      ss += __shfl_down(ss, off);
    }
    int lane = t & 63, wid = t >> 6;
    if (lane == 0) { rs[wid] = s; rq[wid] = ss; }
    __syncthreads();
    float S = rs[0] + rs[1] + rs[2] + rs[3];
    float Q = rq[0] + rq[1] + rq[2] + rq[3];
    float mean = S * (1.f / 2048.f);
    float var = Q * (1.f / 2048.f) - mean * mean;
    float rstd = rsqrtf(var + 1e-5f);
    float4 g0 = *(const float4*)(g + t * 8);
    float4 g1 = *(const float4*)(g + t * 8 + 4);
    float4 b0 = *(const float4*)(bb + t * 8);
    float4 b1 = *(const float4*)(bb + t * 8 + 4);
    float gg[8] = {g0.x, g0.y, g0.z, g0.w, g1.x, g1.y, g1.z, g1.w};
    float bv[8] = {b0.x, b0.y, b0.z, b0.w, b1.x, b1.y, b1.z, b1.w};
    uint4 ov; u16* po = (u16*)&ov;
#pragma unroll
    for (int j = 0; j < 8; ++j)
      po[j] = f2bf((x[j] - mean) * rstd * gg[j] + bv[j]);
    *(uint4*)(yn + (size_t)row * 2048 + t * 8) = ov;
  } else {
    // ---- cast f32 -> bf16, 8 elems/thread ----
    int i = (bid - 14336) * 256 + t;
    float4 a = *(const float4*)(vf + (size_t)i * 8);
    float4 b = *(const float4*)(vf + (size_t)i * 8 + 4);
    uint4 ov; u16* po = (u16*)&ov;
    po[0] = f2bf(a.x); po[1] = f2bf(a.y); po[2] = f2bf(a.z); po[3] = f2bf(a.w);
    po[4] = f2bf(b.x); po[5] = f2bf(b.y); po[6] = f2bf(b.z); po[7] = f2bf(b.w);
    *(uint4*)(vfb + (size_t)i * 8) = ov;
  }
}

// ================= GEMM core: 2-buffer counted-vmcnt pipeline (BK=64) =================
// Round-9/15/17 proven best (46.8 us O-proj): per iter s_waitcnt vmcnt(8) [oldest
// tile's 8 calls done; younger tile's 8 stay in flight] -> s_barrier -> ds_read+MFMA ->
// lgkmcnt(0) -> s_barrier -> stage(t+2). row&7 swizzle: 0 conflicts measured.
__device__ __forceinline__ void gemm_pipe(const u16* __restrict__ A,
                                          const u16* __restrict__ Bt,
                                          int K, int m0, int n0,
                                          int wm, int wn, int lr, int lg,
                                          int wid, int lane,
                                          f32x4 (&acc)[4][4]) {
  __shared__ __align__(16) u16 As[2][128 * 64];
  __shared__ __align__(16) u16 Bs[2][128 * 64];
  int sk = lr & 7;
  int srow[4], scol[4], sbase[4];
#pragma unroll
  for (int j = 0; j < 4; ++j) {
    int s0 = (wid * 4 + j) * 64;
    int s = s0 + lane;
    srow[j] = s >> 3;
    scol[j] = ((s & 7) ^ (srow[j] & 7)) * 8;
    sbase[j] = s0 * 8;
  }
  int nk = K >> 6;
#pragma unroll
  for (int pt = 0; pt < 2; ++pt)
#pragma unroll
    for (int j = 0; j < 4; ++j) {
      gl_lds16(A + (size_t)(m0 + srow[j]) * K + pt * 64 + scol[j], As[pt] + sbase[j]);
      gl_lds16(Bt + (size_t)(n0 + srow[j]) * K + pt * 64 + scol[j], Bs[pt] + sbase[j]);
    }
  for (int tt = 0; tt < nk; ++tt) {
    if (tt + 1 < nk)
      asm volatile("s_waitcnt vmcnt(8)" ::: "memory");   // oldest tile done
    else
      asm volatile("s_waitcnt vmcnt(0)" ::: "memory");
    __builtin_amdgcn_s_barrier();
    __builtin_amdgcn_sched_barrier(0);
    const u16* as = As[tt & 1];
    const u16* bs = Bs[tt & 1];
#pragma unroll
    for (int kk = 0; kk < 2; ++kk) {
      bfrag a[4], b[4];
#pragma unroll
      for (int i = 0; i < 4; ++i)
        a[i] = *(const bfrag*)(as + (wm * 64 + i * 16 + lr) * 64 + (((kk * 4 + lg) ^ sk) * 8));
#pragma unroll
      for (int j = 0; j < 4; ++j)
        b[j] = *(const bfrag*)(bs + (wn * 64 + j * 16 + lr) * 64 + (((kk * 4 + lg) ^ sk) * 8));
      __builtin_amdgcn_s_setprio(1);
#pragma unroll
      for (int i = 0; i < 4; ++i)
#pragma unroll
        for (int j = 0; j < 4; ++j)
          acc[i][j] = mfma16(a[i], b[j], acc[i][j]);
      __builtin_amdgcn_s_setprio(0);
    }
    asm volatile("s_waitcnt lgkmcnt(0)" ::: "memory");
    __builtin_amdgcn_s_barrier();
    __builtin_amdgcn_sched_barrier(0);
    if (tt + 2 < nk) {
      int k0 = (tt + 2) * 64;
#pragma unroll
      for (int j = 0; j < 4; ++j) {
        gl_lds16(A + (size_t)(m0 + srow[j]) * K + k0 + scol[j], As[tt & 1] + sbase[j]);
        gl_lds16(Bt + (size_t)(n0 + srow[j]) * K + k0 + scol[j], Bs[tt & 1] + sbase[j]);
      }
    }
  }
}

template <bool F32OUT>
__global__ __launch_bounds__(256) void k_gemm_bt(const u16* __restrict__ A,
                                                 const u16* __restrict__ Bt,
                                                 void* __restrict__ Cv,
                                                 int M, int N, int K, float scale) {
  int t = threadIdx.x, lane = t & 63, wid = t >> 6;
  int wm = wid >> 1, wn = wid & 1;
  int bx = blockIdx.x, by = blockIdx.y;
  xcd_swizzle(bx, by);
  int m0 = by * 128, n0 = bx * 128;
  int lr = lane & 15, lg = lane >> 4;
  f32x4 acc[4][4];
#pragma unroll
  for (int i = 0; i < 4; ++i)
#pragma unroll
    for (int j = 0; j < 4; ++j) acc[i][j] = (f32x4){0.f, 0.f, 0.f, 0.f};

  gemm_pipe(A, Bt, K, m0, n0, wm, wn, lr, lg, wid, lane, acc);

#pragma unroll
  for (int i = 0; i < 4; ++i)
#pragma unroll
    for (int j = 0; j < 4; ++j) {
      int r0 = m0 + wm * 64 + i * 16 + lg * 4;
      int c0 = n0 + wn * 64 + j * 16 + lr;
#pragma unroll
      for (int r = 0; r < 4; ++r) {
        float v = scale * acc[i][j][r];
        if (F32OUT)
          ((float*)Cv)[(size_t)(r0 + r) * N + c0] = v;
        else
          ((u16*)Cv)[(size_t)(r0 + r) * N + c0] = f2bf(v);
      }
    }
}

// KV GEMM: K=1024; cols [0,1024) -> Kb; cols [1024,2048): V pre-transposed into
// vtb[(b*16+h)*64 + d][512] (packed 8B stores).
__global__ __launch_bounds__(256) void k_gemm_kv(const u16* __restrict__ A,
                                                 const u16* __restrict__ Bt,
                                                 u16* __restrict__ Kb,
                                                 u16* __restrict__ Vtb) {
  const int K = 1024;
  int t = threadIdx.x, lane = t & 63, wid = t >> 6;
  int wm = wid >> 1, wn = wid & 1;
  int bx = blockIdx.x, by = blockIdx.y;
  xcd_swizzle(bx, by);
  int m0 = by * 128, n0 = bx * 128;
  int lr = lane & 15, lg = lane >> 4;
  f32x4 acc[4][4];
#pragma unroll
  for (int i = 0; i < 4; ++i)
#pragma unroll
    for (int j = 0; j < 4; ++j) acc[i][j] = (f32x4){0.f, 0.f, 0.f, 0.f};

  gemm_pipe(A, Bt, K, m0, n0, wm, wn, lr, lg, wid, lane, acc);

#pragma unroll
  for (int i = 0; i < 4; ++i)
#pragma unroll
    for (int j = 0; j < 4; ++j) {
      int r0 = m0 + wm * 64 + i * 16 + lg * 4;
      int c0 = n0 + wn * 64 + j * 16 + lr;
      if (c0 < 1024) {
#pragma unroll
        for (int r = 0; r < 4; ++r)
          Kb[(size_t)(r0 + r) * 1024 + c0] = f2bf(acc[i][j][r]);
      } else {
        int d = c0 - 1024;
        int hh = d >> 6, dd = d & 63;
        int bq = r0 >> 9, kvp = r0 & 511;
        u16x4 pk;
#pragma unroll
        for (int r = 0; r < 4; ++r) pk[r] = f2bf(acc[i][j][r]);
        *(u16x4*)(Vtb + ((size_t)(bq * 16 + hh) * 64 + dd) * 512 + kvp) = pk;
      }
    }
}

// ---------------- fused attention (swapped-QK^T, P in registers, dbuf K/V) ----------------
// grid: (16 q-chunks of 128, 64 = b*16+h). 4 waves, each wave 32 q-rows. KVBLK=128.
__global__ __launch_bounds__(256, 2) void k_attn(const u16* __restrict__ q,
                                                 const u16* __restrict__ kb,
                                                 const u16* __restrict__ vt,
                                                 u16* __restrict__ ao) {
  __shared__ __align__(16) u16 Ks[2][128 * 64];   // [kv][d], swz key row&7
  __shared__ __align__(16) u16 Vt[2][64 * 128];   // [d][kv], swz key d&7
  int t = threadIdx.x, lane = t & 63, wid = t >> 6;
  int lr = lane & 15, lg = lane >> 4;
  int sk = lr & 7;
  int a_ = lg >> 1, b_ = lg & 1;
  int bh = blockIdx.y, b = bh >> 4, h = bh & 15;
  int q0 = blockIdx.x * 128 + wid * 32;

  const u16* qg = q + (size_t)(b * 2048 + q0) * 1024 + h * 64;
  bfrag qf[2][2];
#pragma unroll
  for (int rt = 0; rt < 2; ++rt)
#pragma unroll
    for (int kk = 0; kk < 2; ++kk)
      qf[rt][kk] = *(const bfrag*)(qg + (size_t)(rt * 16 + lr) * 1024 + kk * 32 + lg * 8);

  f32x4 o[2][4];
#pragma unroll
  for (int rt = 0; rt < 2; ++rt)
#pragma unroll
    for (int dt = 0; dt < 4; ++dt) o[rt][dt] = (f32x4){0.f, 0.f, 0.f, 0.f};
  float m_s[2] = {-1e30f, -1e30f}, l_s[2] = {0.f, 0.f};

  const u16* kgb = kb + (size_t)(b * 512) * 1024 + h * 64;
  const u16* vgb = vt + (size_t)bh * 64 * 512;

  int krow[4], kcol[4], kbase[4];
#pragma unroll
  for (int j = 0; j < 4; ++j) {
    int g = wid * 4 + j;
    int s = g * 64 + lane;
    krow[j] = s >> 3;
    kcol[j] = ((s & 7) ^ (krow[j] & 7)) * 8;
    kbase[j] = g * 512;
  }

#pragma unroll
  for (int j = 0; j < 4; ++j)
    gl_lds16(kgb + (size_t)krow[j] * 1024 + kcol[j], Ks[0] + kbase[j]);
#pragma unroll
  for (int j = 0; j < 4; ++j) {
    int g = wid * 4 + j;
    int d = g * 4 + (lane >> 4);
    int p = lane & 15;
    gl_lds16(vgb + (size_t)d * 512 + ((p ^ (d & 7)) * 8), Vt[0] + g * 512);
  }
  __syncthreads();

  for (int it = 0; it < 4; ++it) {
    int cur = it & 1;
    if (it + 1 < 4) {
      int kv1 = (it + 1) * 128;
#pragma unroll
      for (int j = 0; j < 4; ++j)
        gl_lds16(kgb + (size_t)(kv1 + krow[j]) * 1024 + kcol[j], Ks[cur ^ 1] + kbase[j]);
#pragma unroll
      for (int j = 0; j < 4; ++j) {
        int g = wid * 4 + j;
        int d = g * 4 + (lane >> 4);
        int p = lane & 15;
        gl_lds16(vgb + (size_t)d * 512 + kv1 + ((p ^ (d & 7)) * 8), Vt[cur ^ 1] + g * 512);
      }
    }
    const u16* ks = Ks[cur];
    const u16* vtl = Vt[cur];

    f32x4 s[2][8];
#pragma unroll
    for (int rt = 0; rt < 2; ++rt)
#pragma unroll
      for (int ct = 0; ct < 8; ++ct) s[rt][ct] = (f32x4){0.f, 0.f, 0.f, 0.f};
    __builtin_amdgcn_s_setprio(1);
#pragma unroll
    for (int ct = 0; ct < 8; ++ct)
#pragma unroll
      for (int kk = 0; kk < 2; ++kk) {
        bfrag kf = *(const bfrag*)(ks + (ct * 16 + lr) * 64 + (((kk * 4 + lg) ^ sk) * 8));
        s[0][ct] = mfma16(kf, qf[0][kk], s[0][ct]);
        s[1][ct] = mfma16(kf, qf[1][kk], s[1][ct]);
      }
    __builtin_amdgcn_s_setprio(0);

    bfrag pf[2][4];
#pragma unroll
    for (int rt = 0; rt < 2; ++rt) {
      float mloc = -1e30f;
#pragma unroll
      for (int ct = 0; ct < 8; ++ct)
#pragma unroll
        for (int r = 0; r < 4; ++r) mloc = fmaxf(mloc, s[rt][ct][r]);
      mloc = fmaxf(mloc, __shfl_xor(mloc, 16));
      mloc = fmaxf(mloc, __shfl_xor(mloc, 32));
      float mn = fmaxf(m_s[rt], mloc);
      float scq = __expf(m_s[rt] - mn);
      float ps = 0.f;
#pragma unroll
      for (int ct = 0; ct < 8; ++ct)
#pragma unroll
        for (int r = 0; r < 4; ++r) {
          float p = __expf(s[rt][ct][r] - mn);
          s[rt][ct][r] = p;
          ps += p;
        }
      ps += __shfl_xor(ps, 16);
      ps += __shfl_xor(ps, 32);
      l_s[rt] = l_s[rt] * scq + ps;
      m_s[rt] = mn;
      float sc4[4];
#pragma unroll
      for (int r = 0; r < 4; ++r) sc4[r] = __shfl(scq, (lane & 48) | (lg * 4 + r));
#pragma unroll
      for (int dt = 0; dt < 4; ++dt)
#pragma unroll
        for (int r = 0; r < 4; ++r) o[rt][dt][r] *= sc4[r];

      unsigned w0[8], w1[8];
#pragma unroll
      for (int ct = 0; ct < 8; ++ct) {
        w0[ct] = packbf(s[rt][ct][0], s[rt][ct][1]);
        w1[ct] = packbf(s[rt][ct][2], s[rt][ct][3]);
      }
#pragma unroll
      for (int kt = 0; kt < 4; ++kt) {
        unsigned c0w0 = w0[2 * kt], c0w1 = w1[2 * kt];
        unsigned c1w0 = w0[2 * kt + 1], c1w1 = w1[2 * kt + 1];
        unsigned s0 = a_ ? c0w0 : c1w0;
        unsigned s1 = a_ ? c0w1 : c1w1;
        unsigned k0 = a_ ? c1w0 : c0w0;
        unsigned k1 = a_ ? c1w1 : c0w1;
        unsigned r0 = (unsigned)__shfl_xor((int)s0, 32);
        unsigned r1 = (unsigned)__shfl_xor((int)s1, 32);
        unsigned x0 = (a_ == b_) ? r0 : k0;
        unsigned x1 = (a_ == b_) ? r1 : k1;
        unsigned kk0 = (a_ == b_) ? k0 : r0;
        unsigned kk1 = (a_ == b_) ? k1 : r1;
        unsigned q0_ = (unsigned)__shfl_xor((int)x0, 16);
        unsigned q1_ = (unsigned)__shfl_xor((int)x1, 16);
        union { unsigned u[4]; bfrag f; } uf;
        uf.u[0] = b_ ? q0_ : kk0;
        uf.u[1] = b_ ? q1_ : kk1;
        uf.u[2] = b_ ? kk0 : q0_;
        uf.u[3] = b_ ? kk1 : q1_;
        pf[rt][kt] = uf.f;
      }
    }

    __builtin_amdgcn_s_setprio(1);
#pragma unroll
    for (int dt = 0; dt < 4; ++dt)
#pragma unroll
      for (int kt = 0; kt < 4; ++kt) {
        int d = dt * 16 + lr;
        bfrag vfb2 = *(const bfrag*)(vtl + d * 128 + (((kt * 4 + lg) ^ (d & 7)) * 8));
        o[0][dt] = mfma16(pf[0][kt], vfb2, o[0][dt]);
        o[1][dt] = mfma16(pf[1][kt], vfb2, o[1][dt]);
      }
    __builtin_amdgcn_s_setprio(0);

    if (it + 1 < 4) __syncthreads();
  }

#pragma unroll
  for (int rt = 0; rt < 2; ++rt) {
    float invq = 1.f / l_s[rt];
    float i4[4];
#pragma unroll
    for (int r = 0; r < 4; ++r) i4[r] = __shfl(invq, (lane & 48) | (lg * 4 + r));
#pragma unroll
    for (int dt = 0; dt < 4; ++dt)
#pragma unroll
      for (int r = 0; r < 4; ++r)
        ao[(size_t)(b * 2048 + q0 + rt * 16 + lg * 4 + r) * 1024 + h * 64 + dt * 16 + lr] =
            f2bf(o[rt][dt][r] * i4[r]);
  }
}

extern "C" void kernel_launch(void* const* d_in, const int* in_sizes, int n_in,
                              void* d_out, int out_size, void* d_ws, size_t ws_size,
                              hipStream_t stream) {
  const float* y   = (const float*)d_in[0];
  const float* vf  = (const float*)d_in[1];
  const float* g   = (const float*)d_in[2];
  const float* bb  = (const float*)d_in[3];
  const float* Wq  = (const float*)d_in[4];
  const float* Wkv = (const float*)d_in[5];
  const float* Wo  = (const float*)d_in[6];
  float* out = (float*)d_out;
  char* ws = (char*)d_ws;

  u16* qb   = (u16*)(ws + 0ull);          // 8192x1024  (16 MB)
  u16* kbuf = (u16*)(ws + 16777216ull);   // 2048x1024  ( 4 MB) K
  u16* vtb  = (u16*)(ws + 20971520ull);   // 64*64x512  ( 4 MB) V^T per (b,h)
  u16* aob  = (u16*)(ws + 25165824ull);   // 8192x1024  (16 MB)
  u16* wqT  = (u16*)(ws + 41943040ull);   // 1024x2048  ( 4 MB)
  u16* wkvT = (u16*)(ws + 46137344ull);   // 2048x1024  ( 4 MB)
  u16* woT  = (u16*)(ws + 50331648ull);   // 2048x1024  ( 4 MB)
  u16* vfb  = (u16*)(ws + 54525952ull);   // 2048x1024  ( 4 MB)
  // yn (8192x2048 bf16 = 32 MB) lives in d_out; consumed by Q-GEMM, then d_out
  // is fully overwritten by the final GEMM. Deterministic across replays.
  u16* yn = (u16*)d_out;

  // fused preamble: transposes + LN + cast in one launch (15360 blocks)
  k_pre<<<15360, 256, 0, stream>>>(Wq, Wkv, Wo, wqT, wkvT, woT, y, g, bb, yn, vf, vfb);
  // q = LN(y) @ Wq * 1/sqrt(64)
  k_gemm_bt<false><<<dim3(1024 / 128, 8192 / 128, 1), 256, 0, stream>>>(yn, wqT, qb, 8192, 1024, 2048, 0.125f);
  // kv = vis @ Wkv, split into K and pre-transposed V
  k_gemm_kv<<<dim3(2048 / 128, 2048 / 128, 1), 256, 0, stream>>>(vfb, wkvT, kbuf, vtb);
  k_attn<<<dim3(16, 64, 1), 256, 0, stream>>>(qb, kbuf, vtb, aob);
  // out = ao @ Wo (f32 out)
  k_gemm_bt<true><<<dim3(2048 / 128, 8192 / 128, 1), 256, 0, stream>>>(aob, woT, out, 8192, 2048, 1024, 1.0f);
}

// Round 19
// 162.059 us; speedup vs baseline: 1.0572x; 1.0057x over previous
//
#include <hip/hip_runtime.h>
#include <stdint.h>

typedef unsigned short u16;
typedef __bf16 bfrag __attribute__((ext_vector_type(8)));   // 8 x bf16 = 4 VGPRs (MFMA A/B frag)
typedef float f32x4 __attribute__((ext_vector_type(4)));    // MFMA C/D frag
typedef u16 u16x4 __attribute__((ext_vector_type(4)));

__device__ __forceinline__ float bf2f(u16 u) {
  union { unsigned i; float f; } x; x.i = ((unsigned)u) << 16; return x.f;
}
__device__ __forceinline__ u16 f2bf(float f) {
  union { unsigned i; float f; } x; x.f = f;
  unsigned r = x.i + 0x7fffu + ((x.i >> 16) & 1u);   // RNE
  return (u16)(r >> 16);
}
// pure-C bf16 pair pack (inline-asm cvt_pk was implicated in the round-5 failure)
__device__ __forceinline__ unsigned packbf(float lo, float hi) {
  return (unsigned)f2bf(lo) | ((unsigned)f2bf(hi) << 16);
}

__device__ __forceinline__ f32x4 mfma16(bfrag a, bfrag b, f32x4 c) {
  return __builtin_amdgcn_mfma_f32_16x16x32_bf16(a, b, c, 0, 0, 0);
}

// async global->LDS, 16B per lane. LDS dest = wave-uniform base + lane*16.
__device__ __forceinline__ void gl_lds16(const u16* g, const u16* l) {
  __builtin_amdgcn_global_load_lds(
      (const __attribute__((address_space(1))) unsigned int*)g,
      (__attribute__((address_space(3))) unsigned int*)l, 16, 0, 0);
}

// XCD-bijective block swizzle (nwg must be a multiple of 8 — all our grids are).
__device__ __forceinline__ void xcd_swizzle(int& bx, int& by) {
  int gx = gridDim.x, nwg = gx * gridDim.y;
  int flat = by * gx + bx;
  int cpx = nwg >> 3;
  int swz = (flat & 7) * cpx + (flat >> 3);
  bx = swz % gx;
  by = swz / gx;
}

// ================= fused preamble: weight transposes + vf cast + LayerNorm =================
// Blocks [0,6144): 3x weight transpose (32x32 tiles, 2048 tiles/seg).
// Blocks [6144,14336): LayerNorm rows (8192).
// Blocks [14336,15360): vf f32->bf16 cast (1024 blocks x 2048 elems).
// All segments independent; block-uniform branches; outputs consumed by later kernels.
__global__ __launch_bounds__(256) void k_pre(const float* __restrict__ Wq,
                                             const float* __restrict__ Wkv,
                                             const float* __restrict__ Wo,
                                             u16* __restrict__ wqT,
                                             u16* __restrict__ wkvT,
                                             u16* __restrict__ woT,
                                             const float* __restrict__ y,
                                             const float* __restrict__ g,
                                             const float* __restrict__ bb,
                                             u16* __restrict__ yn,
                                             const float* __restrict__ vf,
                                             u16* __restrict__ vfb) {
  __shared__ u16 tile[32][33];
  __shared__ float rs[4], rq[4];
  int bid = blockIdx.x;
  int t = threadIdx.x;

  if (bid < 6144) {
    // ---- weight transpose: in (R x C) f32 -> out (C x R) bf16 ----
    int seg = bid >> 11, tt = bid & 2047;
    const float* in;
    u16* out;
    int R, C, bx, by;
    if (seg == 0)      { in = Wq;  out = wqT;  R = 2048; C = 1024; bx = tt & 31; by = tt >> 5; }
    else if (seg == 1) { in = Wkv; out = wkvT; R = 1024; C = 2048; bx = tt & 63; by = tt >> 6; }
    else               { in = Wo;  out = woT;  R = 1024; C = 2048; bx = tt & 63; by = tt >> 6; }
    int c0 = bx * 32, r0 = by * 32;
    int tx = t & 31, ty = t >> 5;   // flat 256 -> (32,8)
#pragma unroll
    for (int i = 0; i < 4; ++i)
      tile[ty + i * 8][tx] = f2bf(in[(size_t)(r0 + ty + i * 8) * C + c0 + tx]);
    __syncthreads();
#pragma unroll
    for (int i = 0; i < 4; ++i)
      out[(size_t)(c0 + ty + i * 8) * R + r0 + tx] = tile[tx][ty + i * 8];
  } else if (bid < 14336) {
    // ---- LayerNorm over last dim (2048), f32 in -> bf16 out ----
    int row = bid - 6144;
    const float* yr = y + (size_t)row * 2048 + t * 8;
    float4 v0 = *(const float4*)(yr);
    float4 v1 = *(const float4*)(yr + 4);
    float x[8] = {v0.x, v0.y, v0.z, v0.w, v1.x, v1.y, v1.z, v1.w};
    float s = 0.f, ss = 0.f;
#pragma unroll
    for (int j = 0; j < 8; ++j) { s += x[j]; ss += x[j] * x[j]; }
#pragma unroll
    for (int off = 32; off > 0; off >>= 1) {
      s += __shfl_down(s, off);
      ss += __shfl_down(ss, off);
    }
    int lane = t & 63, wid = t >> 6;
    if (lane == 0) { rs[wid] = s; rq[wid] = ss; }
    __syncthreads();
    float S = rs[0] + rs[1] + rs[2] + rs[3];
    float Q = rq[0] + rq[1] + rq[2] + rq[3];
    float mean = S * (1.f / 2048.f);
    float var = Q * (1.f / 2048.f) - mean * mean;
    float rstd = rsqrtf(var + 1e-5f);
    float4 g0 = *(const float4*)(g + t * 8);
    float4 g1 = *(const float4*)(g + t * 8 + 4);
    float4 b0 = *(const float4*)(bb + t * 8);
    float4 b1 = *(const float4*)(bb + t * 8 + 4);
    float gg[8] = {g0.x, g0.y, g0.z, g0.w, g1.x, g1.y, g1.z, g1.w};
    float bv[8] = {b0.x, b0.y, b0.z, b0.w, b1.x, b1.y, b1.z, b1.w};
    uint4 ov; u16* po = (u16*)&ov;
#pragma unroll
    for (int j = 0; j < 8; ++j)
      po[j] = f2bf((x[j] - mean) * rstd * gg[j] + bv[j]);
    *(uint4*)(yn + (size_t)row * 2048 + t * 8) = ov;
  } else {
    // ---- cast f32 -> bf16, 8 elems/thread ----
    int i = (bid - 14336) * 256 + t;
    float4 a = *(const float4*)(vf + (size_t)i * 8);
    float4 b = *(const float4*)(vf + (size_t)i * 8 + 4);
    uint4 ov; u16* po = (u16*)&ov;
    po[0] = f2bf(a.x); po[1] = f2bf(a.y); po[2] = f2bf(a.z); po[3] = f2bf(a.w);
    po[4] = f2bf(b.x); po[5] = f2bf(b.y); po[6] = f2bf(b.z); po[7] = f2bf(b.w);
    *(uint4*)(vfb + (size_t)i * 8) = ov;
  }
}

// ================= GEMM core: 2-buffer counted-vmcnt pipeline (BK=64) =================
// Round-9/15/17/18 proven best (46.8 us O-proj): per iter s_waitcnt vmcnt(8) [oldest
// tile's 8 calls done; younger tile's 8 stay in flight] -> s_barrier -> ds_read+MFMA ->
// lgkmcnt(0) -> s_barrier -> stage(t+2). row&7 swizzle: 0 conflicts measured.
__device__ __forceinline__ void gemm_pipe(const u16* __restrict__ A,
                                          const u16* __restrict__ Bt,
                                          int K, int m0, int n0,
                                          int wm, int wn, int lr, int lg,
                                          int wid, int lane,
                                          f32x4 (&acc)[4][4]) {
  __shared__ __align__(16) u16 As[2][128 * 64];
  __shared__ __align__(16) u16 Bs[2][128 * 64];
  int sk = lr & 7;
  int srow[4], scol[4], sbase[4];
#pragma unroll
  for (int j = 0; j < 4; ++j) {
    int s0 = (wid * 4 + j) * 64;
    int s = s0 + lane;
    srow[j] = s >> 3;
    scol[j] = ((s & 7) ^ (srow[j] & 7)) * 8;
    sbase[j] = s0 * 8;
  }
  int nk = K >> 6;
#pragma unroll
  for (int pt = 0; pt < 2; ++pt)
#pragma unroll
    for (int j = 0; j < 4; ++j) {
      gl_lds16(A + (size_t)(m0 + srow[j]) * K + pt * 64 + scol[j], As[pt] + sbase[j]);
      gl_lds16(Bt + (size_t)(n0 + srow[j]) * K + pt * 64 + scol[j], Bs[pt] + sbase[j]);
    }
  for (int tt = 0; tt < nk; ++tt) {
    if (tt + 1 < nk)
      asm volatile("s_waitcnt vmcnt(8)" ::: "memory");   // oldest tile done
    else
      asm volatile("s_waitcnt vmcnt(0)" ::: "memory");
    __builtin_amdgcn_s_barrier();
    __builtin_amdgcn_sched_barrier(0);
    const u16* as = As[tt & 1];
    const u16* bs = Bs[tt & 1];
#pragma unroll
    for (int kk = 0; kk < 2; ++kk) {
      bfrag a[4], b[4];
#pragma unroll
      for (int i = 0; i < 4; ++i)
        a[i] = *(const bfrag*)(as + (wm * 64 + i * 16 + lr) * 64 + (((kk * 4 + lg) ^ sk) * 8));
#pragma unroll
      for (int j = 0; j < 4; ++j)
        b[j] = *(const bfrag*)(bs + (wn * 64 + j * 16 + lr) * 64 + (((kk * 4 + lg) ^ sk) * 8));
      __builtin_amdgcn_s_setprio(1);
#pragma unroll
      for (int i = 0; i < 4; ++i)
#pragma unroll
        for (int j = 0; j < 4; ++j)
          acc[i][j] = mfma16(a[i], b[j], acc[i][j]);
      __builtin_amdgcn_s_setprio(0);
    }
    asm volatile("s_waitcnt lgkmcnt(0)" ::: "memory");
    __builtin_amdgcn_s_barrier();
    __builtin_amdgcn_sched_barrier(0);
    if (tt + 2 < nk) {
      int k0 = (tt + 2) * 64;
#pragma unroll
      for (int j = 0; j < 4; ++j) {
        gl_lds16(A + (size_t)(m0 + srow[j]) * K + k0 + scol[j], As[tt & 1] + sbase[j]);
        gl_lds16(Bt + (size_t)(n0 + srow[j]) * K + k0 + scol[j], Bs[tt & 1] + sbase[j]);
      }
    }
  }
}

template <bool F32OUT>
__global__ __launch_bounds__(256) void k_gemm_bt(const u16* __restrict__ A,
                                                 const u16* __restrict__ Bt,
                                                 void* __restrict__ Cv,
                                                 int M, int N, int K, float scale) {
  int t = threadIdx.x, lane = t & 63, wid = t >> 6;
  int wm = wid >> 1, wn = wid & 1;
  int bx = blockIdx.x, by = blockIdx.y;
  xcd_swizzle(bx, by);
  int m0 = by * 128, n0 = bx * 128;
  int lr = lane & 15, lg = lane >> 4;
  f32x4 acc[4][4];
#pragma unroll
  for (int i = 0; i < 4; ++i)
#pragma unroll
    for (int j = 0; j < 4; ++j) acc[i][j] = (f32x4){0.f, 0.f, 0.f, 0.f};

  gemm_pipe(A, Bt, K, m0, n0, wm, wn, lr, lg, wid, lane, acc);

#pragma unroll
  for (int i = 0; i < 4; ++i)
#pragma unroll
    for (int j = 0; j < 4; ++j) {
      int r0 = m0 + wm * 64 + i * 16 + lg * 4;
      int c0 = n0 + wn * 64 + j * 16 + lr;
#pragma unroll
      for (int r = 0; r < 4; ++r) {
        float v = scale * acc[i][j][r];
        if (F32OUT)
          ((float*)Cv)[(size_t)(r0 + r) * N + c0] = v;
        else
          ((u16*)Cv)[(size_t)(r0 + r) * N + c0] = f2bf(v);
      }
    }
}

// KV GEMM: K=1024; cols [0,1024) -> Kb; cols [1024,2048): V pre-transposed into
// vtb[(b*16+h)*64 + d][512] (packed 8B stores).
__global__ __launch_bounds__(256) void k_gemm_kv(const u16* __restrict__ A,
                                                 const u16* __restrict__ Bt,
                                                 u16* __restrict__ Kb,
                                                 u16* __restrict__ Vtb) {
  const int K = 1024;
  int t = threadIdx.x, lane = t & 63, wid = t >> 6;
  int wm = wid >> 1, wn = wid & 1;
  int bx = blockIdx.x, by = blockIdx.y;
  xcd_swizzle(bx, by);
  int m0 = by * 128, n0 = bx * 128;
  int lr = lane & 15, lg = lane >> 4;
  f32x4 acc[4][4];
#pragma unroll
  for (int i = 0; i < 4; ++i)
#pragma unroll
    for (int j = 0; j < 4; ++j) acc[i][j] = (f32x4){0.f, 0.f, 0.f, 0.f};

  gemm_pipe(A, Bt, K, m0, n0, wm, wn, lr, lg, wid, lane, acc);

#pragma unroll
  for (int i = 0; i < 4; ++i)
#pragma unroll
    for (int j = 0; j < 4; ++j) {
      int r0 = m0 + wm * 64 + i * 16 + lg * 4;
      int c0 = n0 + wn * 64 + j * 16 + lr;
      if (c0 < 1024) {
#pragma unroll
        for (int r = 0; r < 4; ++r)
          Kb[(size_t)(r0 + r) * 1024 + c0] = f2bf(acc[i][j][r]);
      } else {
        int d = c0 - 1024;
        int hh = d >> 6, dd = d & 63;
        int bq = r0 >> 9, kvp = r0 & 511;
        u16x4 pk;
#pragma unroll
        for (int r = 0; r < 4; ++r) pk[r] = f2bf(acc[i][j][r]);
        *(u16x4*)(Vtb + ((size_t)(bq * 16 + hh) * 64 + dd) * 512 + kvp) = pk;
      }
    }
}

// ---------------- fused attention (swapped-QK^T, P in registers, dbuf K/V) ----------------
// grid: (16 q-chunks of 128, 64 = b*16+h). 4 waves, each wave 32 q-rows. KVBLK=128.
__global__ __launch_bounds__(256, 2) void k_attn(const u16* __restrict__ q,
                                                 const u16* __restrict__ kb,
                                                 const u16* __restrict__ vt,
                                                 u16* __restrict__ ao) {
  __shared__ __align__(16) u16 Ks[2][128 * 64];   // [kv][d], swz key row&7
  __shared__ __align__(16) u16 Vt[2][64 * 128];   // [d][kv], swz key d&7
  int t = threadIdx.x, lane = t & 63, wid = t >> 6;
  int lr = lane & 15, lg = lane >> 4;
  int sk = lr & 7;
  int a_ = lg >> 1, b_ = lg & 1;
  int bh = blockIdx.y, b = bh >> 4, h = bh & 15;
  int q0 = blockIdx.x * 128 + wid * 32;

  const u16* qg = q + (size_t)(b * 2048 + q0) * 1024 + h * 64;
  bfrag qf[2][2];
#pragma unroll
  for (int rt = 0; rt < 2; ++rt)
#pragma unroll
    for (int kk = 0; kk < 2; ++kk)
      qf[rt][kk] = *(const bfrag*)(qg + (size_t)(rt * 16 + lr) * 1024 + kk * 32 + lg * 8);

  f32x4 o[2][4];
#pragma unroll
  for (int rt = 0; rt < 2; ++rt)
#pragma unroll
    for (int dt = 0; dt < 4; ++dt) o[rt][dt] = (f32x4){0.f, 0.f, 0.f, 0.f};
  float m_s[2] = {-1e30f, -1e30f}, l_s[2] = {0.f, 0.f};

  const u16* kgb = kb + (size_t)(b * 512) * 1024 + h * 64;
  const u16* vgb = vt + (size_t)bh * 64 * 512;

  int krow[4], kcol[4], kbase[4];
#pragma unroll
  for (int j = 0; j < 4; ++j) {
    int g = wid * 4 + j;
    int s = g * 64 + lane;
    krow[j] = s >> 3;
    kcol[j] = ((s & 7) ^ (krow[j] & 7)) * 8;
    kbase[j] = g * 512;
  }

#pragma unroll
  for (int j = 0; j < 4; ++j)
    gl_lds16(kgb + (size_t)krow[j] * 1024 + kcol[j], Ks[0] + kbase[j]);
#pragma unroll
  for (int j = 0; j < 4; ++j) {
    int g = wid * 4 + j;
    int d = g * 4 + (lane >> 4);
    int p = lane & 15;
    gl_lds16(vgb + (size_t)d * 512 + ((p ^ (d & 7)) * 8), Vt[0] + g * 512);
  }
  __syncthreads();

  for (int it = 0; it < 4; ++it) {
    int cur = it & 1;
    if (it + 1 < 4) {
      int kv1 = (it + 1) * 128;
#pragma unroll
      for (int j = 0; j < 4; ++j)
        gl_lds16(kgb + (size_t)(kv1 + krow[j]) * 1024 + kcol[j], Ks[cur ^ 1] + kbase[j]);
#pragma unroll
      for (int j = 0; j < 4; ++j) {
        int g = wid * 4 + j;
        int d = g * 4 + (lane >> 4);
        int p = lane & 15;
        gl_lds16(vgb + (size_t)d * 512 + kv1 + ((p ^ (d & 7)) * 8), Vt[cur ^ 1] + g * 512);
      }
    }
    const u16* ks = Ks[cur];
    const u16* vtl = Vt[cur];

    f32x4 s[2][8];
#pragma unroll
    for (int rt = 0; rt < 2; ++rt)
#pragma unroll
      for (int ct = 0; ct < 8; ++ct) s[rt][ct] = (f32x4){0.f, 0.f, 0.f, 0.f};
    __builtin_amdgcn_s_setprio(1);
#pragma unroll
    for (int ct = 0; ct < 8; ++ct)
#pragma unroll
      for (int kk = 0; kk < 2; ++kk) {
        bfrag kf = *(const bfrag*)(ks + (ct * 16 + lr) * 64 + (((kk * 4 + lg) ^ sk) * 8));
        s[0][ct] = mfma16(kf, qf[0][kk], s[0][ct]);
        s[1][ct] = mfma16(kf, qf[1][kk], s[1][ct]);
      }
    __builtin_amdgcn_s_setprio(0);

    bfrag pf[2][4];
#pragma unroll
    for (int rt = 0; rt < 2; ++rt) {
      float mloc = -1e30f;
#pragma unroll
      for (int ct = 0; ct < 8; ++ct)
#pragma unroll
        for (int r = 0; r < 4; ++r) mloc = fmaxf(mloc, s[rt][ct][r]);
      mloc = fmaxf(mloc, __shfl_xor(mloc, 16));
      mloc = fmaxf(mloc, __shfl_xor(mloc, 32));
      float mn = fmaxf(m_s[rt], mloc);
      float scq = __expf(m_s[rt] - mn);
      float ps = 0.f;
#pragma unroll
      for (int ct = 0; ct < 8; ++ct)
#pragma unroll
        for (int r = 0; r < 4; ++r) {
          float p = __expf(s[rt][ct][r] - mn);
          s[rt][ct][r] = p;
          ps += p;
        }
      ps += __shfl_xor(ps, 16);
      ps += __shfl_xor(ps, 32);
      l_s[rt] = l_s[rt] * scq + ps;
      m_s[rt] = mn;
      float sc4[4];
#pragma unroll
      for (int r = 0; r < 4; ++r) sc4[r] = __shfl(scq, (lane & 48) | (lg * 4 + r));
#pragma unroll
      for (int dt = 0; dt < 4; ++dt)
#pragma unroll
        for (int r = 0; r < 4; ++r) o[rt][dt][r] *= sc4[r];

      unsigned w0[8], w1[8];
#pragma unroll
      for (int ct = 0; ct < 8; ++ct) {
        w0[ct] = packbf(s[rt][ct][0], s[rt][ct][1]);
        w1[ct] = packbf(s[rt][ct][2], s[rt][ct][3]);
      }
#pragma unroll
      for (int kt = 0; kt < 4; ++kt) {
        unsigned c0w0 = w0[2 * kt], c0w1 = w1[2 * kt];
        unsigned c1w0 = w0[2 * kt + 1], c1w1 = w1[2 * kt + 1];
        unsigned s0 = a_ ? c0w0 : c1w0;
        unsigned s1 = a_ ? c0w1 : c1w1;
        unsigned k0 = a_ ? c1w0 : c0w0;
        unsigned k1 = a_ ? c1w1 : c0w1;
        unsigned r0 = (unsigned)__shfl_xor((int)s0, 32);
        unsigned r1 = (unsigned)__shfl_xor((int)s1, 32);
        unsigned x0 = (a_ == b_) ? r0 : k0;
        unsigned x1 = (a_ == b_) ? r1 : k1;
        unsigned kk0 = (a_ == b_) ? k0 : r0;
        unsigned kk1 = (a_ == b_) ? k1 : r1;
        unsigned q0_ = (unsigned)__shfl_xor((int)x0, 16);
        unsigned q1_ = (unsigned)__shfl_xor((int)x1, 16);
        union { unsigned u[4]; bfrag f; } uf;
        uf.u[0] = b_ ? q0_ : kk0;
        uf.u[1] = b_ ? q1_ : kk1;
        uf.u[2] = b_ ? kk0 : q0_;
        uf.u[3] = b_ ? kk1 : q1_;
        pf[rt][kt] = uf.f;
      }
    }

    __builtin_amdgcn_s_setprio(1);
#pragma unroll
    for (int dt = 0; dt < 4; ++dt)
#pragma unroll
      for (int kt = 0; kt < 4; ++kt) {
        int d = dt * 16 + lr;
        bfrag vfb2 = *(const bfrag*)(vtl + d * 128 + (((kt * 4 + lg) ^ (d & 7)) * 8));
        o[0][dt] = mfma16(pf[0][kt], vfb2, o[0][dt]);
        o[1][dt] = mfma16(pf[1][kt], vfb2, o[1][dt]);
      }
    __builtin_amdgcn_s_setprio(0);

    if (it + 1 < 4) __syncthreads();
  }

#pragma unroll
  for (int rt = 0; rt < 2; ++rt) {
    float invq = 1.f / l_s[rt];
    float i4[4];
#pragma unroll
    for (int r = 0; r < 4; ++r) i4[r] = __shfl(invq, (lane & 48) | (lg * 4 + r));
#pragma unroll
    for (int dt = 0; dt < 4; ++dt)
#pragma unroll
      for (int r = 0; r < 4; ++r)
        ao[(size_t)(b * 2048 + q0 + rt * 16 + lg * 4 + r) * 1024 + h * 64 + dt * 16 + lr] =
            f2bf(o[rt][dt][r] * i4[r]);
  }
}

extern "C" void kernel_launch(void* const* d_in, const int* in_sizes, int n_in,
                              void* d_out, int out_size, void* d_ws, size_t ws_size,
                              hipStream_t stream) {
  const float* y   = (const float*)d_in[0];
  const float* vf  = (const float*)d_in[1];
  const float* g   = (const float*)d_in[2];
  const float* bb  = (const float*)d_in[3];
  const float* Wq  = (const float*)d_in[4];
  const float* Wkv = (const float*)d_in[5];
  const float* Wo  = (const float*)d_in[6];
  float* out = (float*)d_out;
  char* ws = (char*)d_ws;

  u16* qb   = (u16*)(ws + 0ull);          // 8192x1024  (16 MB)
  u16* kbuf = (u16*)(ws + 16777216ull);   // 2048x1024  ( 4 MB) K
  u16* vtb  = (u16*)(ws + 20971520ull);   // 64*64x512  ( 4 MB) V^T per (b,h)
  u16* aob  = (u16*)(ws + 25165824ull);   // 8192x1024  (16 MB)
  u16* wqT  = (u16*)(ws + 41943040ull);   // 1024x2048  ( 4 MB)
  u16* wkvT = (u16*)(ws + 46137344ull);   // 2048x1024  ( 4 MB)
  u16* woT  = (u16*)(ws + 50331648ull);   // 2048x1024  ( 4 MB)
  u16* vfb  = (u16*)(ws + 54525952ull);   // 2048x1024  ( 4 MB)
  // yn (8192x2048 bf16 = 32 MB) lives in d_out; consumed by Q-GEMM, then d_out
  // is fully overwritten by the final GEMM. Deterministic across replays.
  u16* yn = (u16*)d_out;

  // fused preamble: transposes + LN + cast in one launch (15360 blocks)
  k_pre<<<15360, 256, 0, stream>>>(Wq, Wkv, Wo, wqT, wkvT, woT, y, g, bb, yn, vf, vfb);
  // q = LN(y) @ Wq * 1/sqrt(64)
  k_gemm_bt<false><<<dim3(1024 / 128, 8192 / 128, 1), 256, 0, stream>>>(yn, wqT, qb, 8192, 1024, 2048, 0.125f);
  // kv = vis @ Wkv, split into K and pre-transposed V
  k_gemm_kv<<<dim3(2048 / 128, 2048 / 128, 1), 256, 0, stream>>>(vfb, wkvT, kbuf, vtb);
  k_attn<<<dim3(16, 64, 1), 256, 0, stream>>>(qb, kbuf, vtb, aob);
  // out = ao @ Wo (f32 out)
  k_gemm_bt<true><<<dim3(2048 / 128, 8192 / 128, 1), 256, 0, stream>>>(aob, woT, out, 8192, 2048, 1024, 1.0f);
}